// Round 1
// baseline (5590.468 us; speedup 1.0000x reference)
//
#include <hip/hip_runtime.h>
#include <math.h>

#define S3 17576   // 26^3
#define SP 16384   // 128^2
#define PTOT 98688

// dp slice offsets
#define OFF_W1 0
#define OFF_B1 28672
#define OFF_W2 28736
#define OFF_B2 32832
#define OFF_W3 32896
#define OFF_B3 41088
#define OFF_WSH 41216
#define OFF_BSH 98560

// ---------------------------------------------------------------------------
// K1 / K7: fused 1x1-conv (optional) + rb2d over 64-pixel tiles
// MODE 0: src = x (B,3,SP) -> dst = carry (B,64,S3), first SP pixels
// MODE 1: src = carry (B,64,S3) -> dst = f1 (B,64,SP)
// ---------------------------------------------------------------------------
template<int MODE>
__global__ __launch_bounds__(256) void k_rb2d(
    const float* __restrict__ src, const float* __restrict__ cw,
    const float* __restrict__ cb, const float* __restrict__ w1,
    const float* __restrict__ b1, const float* __restrict__ w2,
    const float* __restrict__ b2, float* __restrict__ dst)
{
    const int b = blockIdx.y;
    const int pix0 = blockIdx.x * 64;
    __shared__ float wsBuf[4096];
    __shared__ float hA[64 * 65];
    __shared__ float hB[64 * 65];
    __shared__ float xt[3 * 64];
    __shared__ float bias1[64], bias2[64], cbias[64], cwS[192];
    const int tid = threadIdx.x;

    for (int i = tid; i < 4096; i += 256) wsBuf[i] = w1[i];
    if (tid < 64) { bias1[tid] = b1[tid]; bias2[tid] = b2[tid]; }
    if (MODE == 0) {
        if (tid < 192) cwS[tid] = cw[tid];
        if (tid < 64) cbias[tid] = cb[tid];
        for (int i = tid; i < 192; i += 256)
            xt[i] = src[((size_t)b * 3 + (i >> 6)) * SP + pix0 + (i & 63)];
    }
    __syncthreads();
    // stage 1: hA
    for (int i = tid; i < 4096; i += 256) {
        int c = i >> 6, p = i & 63;
        float v;
        if (MODE == 0) {
            v = cbias[c] + cwS[c * 3 + 0] * xt[p] + cwS[c * 3 + 1] * xt[64 + p]
                + cwS[c * 3 + 2] * xt[128 + p];
        } else {
            v = src[((size_t)b * 64 + c) * S3 + pix0 + p];
        }
        hA[c * 65 + p] = v;
    }
    __syncthreads();
    // stage 2: hB = lrelu(w1 @ hA + b1)
    for (int i = tid; i < 4096; i += 256) {
        int c = i >> 6, p = i & 63;
        float acc = bias1[c];
        #pragma unroll 8
        for (int k = 0; k < 64; k++) acc += wsBuf[c * 64 + k] * hA[k * 65 + p];
        hB[c * 65 + p] = acc >= 0.f ? acc : 0.2f * acc;
    }
    __syncthreads();
    // reload weights with w2
    for (int i = tid; i < 4096; i += 256) wsBuf[i] = w2[i];
    __syncthreads();
    // stage 3: dst = hA + w2 @ hB + b2
    for (int i = tid; i < 4096; i += 256) {
        int c = i >> 6, p = i & 63;
        float acc = bias2[c];
        #pragma unroll 8
        for (int k = 0; k < 64; k++) acc += wsBuf[c * 64 + k] * hB[k * 65 + p];
        acc += hA[c * 65 + p];
        if (MODE == 0) dst[((size_t)b * 64 + c) * S3 + pix0 + p] = acc;
        else           dst[((size_t)b * 64 + c) * SP + pix0 + p] = acc;
    }
}

// ---------------------------------------------------------------------------
// K2: hypernet GEMV dp[b][j] = hyper_b[j] + sum_k inj_lat[b][k] * hyper_w[k][j]
// ---------------------------------------------------------------------------
__global__ __launch_bounds__(256) void k_hyper(
    const float* __restrict__ lat, const float* __restrict__ hw,
    const float* __restrict__ hb, float* __restrict__ dp)
{
    int j = blockIdx.x * 256 + threadIdx.x;
    if (j >= PTOT) return;
    float a0 = hb[j], a1 = a0, a2 = a0, a3 = a0;
    for (int k = 0; k < 512; k++) {
        float w = hw[(size_t)k * PTOT + j];
        a0 += lat[k] * w;
        a1 += lat[512 + k] * w;
        a2 += lat[1024 + k] * w;
        a3 += lat[1536 + k] * w;
    }
    dp[j] = a0;
    dp[PTOT + j] = a1;
    dp[2 * PTOT + j] = a2;
    dp[3 * PTOT + j] = a3;
}

// ---------------------------------------------------------------------------
// Apack: A' = [w3 | wsh] (B,128,512), bias3 = b3 + bsh (B,128)
// ---------------------------------------------------------------------------
__global__ void k_apack(const float* __restrict__ dp, float* __restrict__ ap,
                        float* __restrict__ b3)
{
    int idx = blockIdx.x * 256 + threadIdx.x;
    if (idx < 262144) {
        int b = idx >> 16, rem = idx & 65535;
        int r = rem >> 9, cc = rem & 511;
        const float* dpb = dp + (size_t)b * PTOT;
        float v = (cc < 64) ? dpb[OFF_W3 + r * 64 + cc]
                            : dpb[OFF_WSH + r * 448 + (cc - 64)];
        ap[idx] = v;
    }
    if (idx < 512) {
        int b = idx >> 7, r = idx & 127;
        b3[idx] = dp[(size_t)b * PTOT + OFF_B3 + r] + dp[(size_t)b * PTOT + OFF_BSH + r];
    }
}

// ---------------------------------------------------------------------------
// K3: sobel conv (sparse taps) + raw copy + per-channel sum/sumsq partials
// grid: (slab=5, c=64, b=4); LDS slab of 10 planes, zero-padded 30x30
// ---------------------------------------------------------------------------
__global__ __launch_bounds__(256) void k_conv(
    const float* __restrict__ carry, float* __restrict__ bg3,
    float* __restrict__ ssum)
{
    const int slab = blockIdx.x, c = blockIdx.y, b = blockIdx.z;
    const int d0 = slab * 6;
    __shared__ float L[10 * 900];
    __shared__ float red[4][14];
    const float* src = carry + ((size_t)b * 64 + c) * S3;
    const int tid = threadIdx.x;

    for (int idx = tid; idx < 9000; idx += 256) {
        int pd = idx / 900, rem = idx % 900;
        int ph = rem / 30, pw = rem % 30;
        int d = d0 + pd - 2, h = ph - 2, w = pw - 2;
        float v = 0.f;
        if (d >= 0 && d < 26 && h >= 0 && h < 26 && w >= 0 && w < 26)
            v = src[d * 676 + h * 26 + w];
        L[idx] = v;
    }
    __syncthreads();

    const float r2 = 0.70710678118654752f;
    const float g5[5] = {-1.f, -r2, 0.f, r2, 1.f};
    const float s5[5] = {0.f, r2, 1.f, r2, 0.f};
    float s[7] = {0, 0, 0, 0, 0, 0, 0};
    float q[7] = {0, 0, 0, 0, 0, 0, 0};
    const size_t pb = ((size_t)b * 512 + 64) * S3;  // base of p rows in bg3

    for (int vox = tid; vox < 6 * 676; vox += 256) {
        int dl = vox / 676, rem = vox % 676;
        int d = d0 + dl;
        if (d < 26) {
            int h = rem / 26, w = rem % 26;
            int base = (dl + 2) * 900 + (h + 2) * 30 + (w + 2);
            int sidx = d * 676 + rem;
            float raw = L[base];
            float o1 = L[base + 900] - L[base - 900];
            float o2 = L[base + 30] - L[base - 30];
            float o3 = L[base + 1] - L[base - 1];
            float a5x = 0.f, a5y = 0.f, a5z = 0.f;
            #pragma unroll
            for (int i = 0; i < 5; i++) {
                #pragma unroll
                for (int j = 0; j < 5; j++) {
                    int o = base + (i - 2) * 900 + (j - 2) * 30;
                    float wx = g5[i] * s5[j];
                    float wy = s5[i] * g5[j];
                    float wz = s5[i] * s5[j];
                    if (wx != 0.f || wy != 0.f) {
                        float rw = r2 * L[o - 1] + L[o] + r2 * L[o + 1];
                        a5x += wx * rw;
                        a5y += wy * rw;
                    }
                    if (wz != 0.f) {
                        float gw = -L[o - 2] - r2 * L[o - 1] + r2 * L[o + 1] + L[o + 2];
                        a5z += wz * gw;
                    }
                }
            }
            bg3[pb + (size_t)c * S3 + sidx] = raw;
            bg3[pb + (size_t)(64 + 3 * c + 0) * S3 + sidx] = o1;
            bg3[pb + (size_t)(64 + 3 * c + 1) * S3 + sidx] = o2;
            bg3[pb + (size_t)(64 + 3 * c + 2) * S3 + sidx] = o3;
            bg3[pb + (size_t)(256 + 3 * c + 0) * S3 + sidx] = a5x;
            bg3[pb + (size_t)(256 + 3 * c + 1) * S3 + sidx] = a5y;
            bg3[pb + (size_t)(256 + 3 * c + 2) * S3 + sidx] = a5z;
            s[0] += raw; q[0] += raw * raw;
            s[1] += o1;  q[1] += o1 * o1;
            s[2] += o2;  q[2] += o2 * o2;
            s[3] += o3;  q[3] += o3 * o3;
            s[4] += a5x; q[4] += a5x * a5x;
            s[5] += a5y; q[5] += a5y * a5y;
            s[6] += a5z; q[6] += a5z * a5z;
        }
    }
    #pragma unroll
    for (int off = 32; off > 0; off >>= 1) {
        #pragma unroll
        for (int i = 0; i < 7; i++) {
            s[i] += __shfl_down(s[i], off);
            q[i] += __shfl_down(q[i], off);
        }
    }
    int wave = tid >> 6, lane = tid & 63;
    if (lane == 0) {
        #pragma unroll
        for (int i = 0; i < 7; i++) { red[wave][i] = s[i]; red[wave][7 + i] = q[i]; }
    }
    __syncthreads();
    if (tid < 14) {
        float t = red[0][tid] + red[1][tid] + red[2][tid] + red[3][tid];
        int slot = tid % 7, isq = tid / 7;
        int ch = (slot == 0) ? c : (slot < 4 ? 64 + 3 * c + (slot - 1)
                                             : 256 + 3 * c + (slot - 4));
        atomicAdd(&ssum[((size_t)b * 448 + ch) * 2 + isq], t);
    }
}

__global__ void k_stats_fin(const float* __restrict__ ssum, float* __restrict__ sm,
                            float* __restrict__ sr)
{
    int i = blockIdx.x * 256 + threadIdx.x;
    if (i < 4 * 448) {
        float su = ssum[i * 2], sq = ssum[i * 2 + 1];
        float m = su * (1.f / (float)S3);
        float v = fmaxf(sq * (1.f / (float)S3) - m * m, 0.f);
        sm[i] = m;
        sr[i] = rsqrtf(v + 1e-5f);
    }
}

// ---------------------------------------------------------------------------
// Batched tiled fp32 GEMM: C[b] = act(A[b] @ B[b] + bias[b])
// tile M=64 x N=128, KT=32.  NORM: 0 none, 1 normalize all B rows,
// 2 normalize B rows >= 64 (stats index row-64).  C row stride = S3.
// ---------------------------------------------------------------------------
template<int ACT, int NORM>
__global__ __launch_bounds__(256) void k_gemm(
    const float* __restrict__ Abase, size_t aStride, int lda,
    const float* __restrict__ Bbase, size_t bStride,
    float* __restrict__ Cbase, size_t cStride,
    const float* __restrict__ biasBase, int biasStride,
    const float* __restrict__ statsM, const float* __restrict__ statsR,
    int K, int Nvalid)
{
    const int b = blockIdx.z, mblk = blockIdx.y;
    const int n0 = blockIdx.x * 128;
    const float* A = Abase + (size_t)b * aStride + (size_t)mblk * 64 * lda;
    const float* Bp = Bbase + (size_t)b * bStride;
    float* C = Cbase + (size_t)b * cStride + (size_t)mblk * 64 * S3;
    const float* bias = biasBase + (size_t)b * biasStride + mblk * 64;
    const float* sm = statsM + (size_t)b * 448;
    const float* sr = statsR + (size_t)b * 448;

    __shared__ __align__(16) float As[32 * 68];
    __shared__ __align__(16) float Bs[32 * 132];
    float acc[8][4];
    #pragma unroll
    for (int j = 0; j < 8; j++)
        #pragma unroll
        for (int i = 0; i < 4; i++) acc[j][i] = 0.f;

    const int tid = threadIdx.x;
    const int tr = tid >> 5, tc = tid & 31;

    for (int k0 = 0; k0 < K; k0 += 32) {
        // A tile 64x32: coalesced global (consecutive k), store As[k][m]
        #pragma unroll
        for (int l = 0; l < 8; l++) {
            int idx = tid + l * 256;
            int kk = idx & 31, m = idx >> 5;
            As[kk * 68 + m] = A[(size_t)m * lda + k0 + kk];
        }
        // B tile 32x128 with optional inorm on load
        #pragma unroll
        for (int l = 0; l < 16; l++) {
            int idx = tid + l * 256;
            int kk = idx >> 7, n = idx & 127;
            int row = k0 + kk;
            int gn = n0 + n;
            float v = (gn < Nvalid) ? Bp[(size_t)row * S3 + gn] : 0.f;
            if (NORM == 1) v = (v - sm[row]) * sr[row];
            else if (NORM == 2) { if (row >= 64) v = (v - sm[row - 64]) * sr[row - 64]; }
            Bs[kk * 132 + n] = v;
        }
        __syncthreads();
        #pragma unroll
        for (int kk = 0; kk < 32; kk++) {
            float4 b4 = *(const float4*)&Bs[kk * 132 + tc * 4];
            float4 a0 = *(const float4*)&As[kk * 68 + tr * 8];
            float4 a1 = *(const float4*)&As[kk * 68 + tr * 8 + 4];
            acc[0][0] += a0.x * b4.x; acc[0][1] += a0.x * b4.y; acc[0][2] += a0.x * b4.z; acc[0][3] += a0.x * b4.w;
            acc[1][0] += a0.y * b4.x; acc[1][1] += a0.y * b4.y; acc[1][2] += a0.y * b4.z; acc[1][3] += a0.y * b4.w;
            acc[2][0] += a0.z * b4.x; acc[2][1] += a0.z * b4.y; acc[2][2] += a0.z * b4.z; acc[2][3] += a0.z * b4.w;
            acc[3][0] += a0.w * b4.x; acc[3][1] += a0.w * b4.y; acc[3][2] += a0.w * b4.z; acc[3][3] += a0.w * b4.w;
            acc[4][0] += a1.x * b4.x; acc[4][1] += a1.x * b4.y; acc[4][2] += a1.x * b4.z; acc[4][3] += a1.x * b4.w;
            acc[5][0] += a1.y * b4.x; acc[5][1] += a1.y * b4.y; acc[5][2] += a1.y * b4.z; acc[5][3] += a1.y * b4.w;
            acc[6][0] += a1.z * b4.x; acc[6][1] += a1.z * b4.y; acc[6][2] += a1.z * b4.z; acc[6][3] += a1.z * b4.w;
            acc[7][0] += a1.w * b4.x; acc[7][1] += a1.w * b4.y; acc[7][2] += a1.w * b4.z; acc[7][3] += a1.w * b4.w;
        }
        __syncthreads();
    }
    #pragma unroll
    for (int j = 0; j < 8; j++) {
        int r = tr * 8 + j;
        float bb = bias[r];
        int gn = n0 + tc * 4;
        if (gn + 3 < Nvalid) {
            float4 v;
            v.x = acc[j][0] + bb; v.y = acc[j][1] + bb;
            v.z = acc[j][2] + bb; v.w = acc[j][3] + bb;
            if (ACT == 1) {
                v.x = v.x >= 0.f ? v.x : 0.2f * v.x;
                v.y = v.y >= 0.f ? v.y : 0.2f * v.y;
                v.z = v.z >= 0.f ? v.z : 0.2f * v.z;
                v.w = v.w >= 0.f ? v.w : 0.2f * v.w;
            }
            *(float4*)&C[(size_t)r * S3 + gn] = v;
        } else {
            #pragma unroll
            for (int i = 0; i < 4; i++) {
                if (gn + i < Nvalid) {
                    float v = acc[j][i] + bb;
                    if (ACT == 1) v = v >= 0.f ? v : 0.2f * v;
                    C[(size_t)r * S3 + gn + i] = v;
                }
            }
        }
    }
}

// ---------------------------------------------------------------------------
// K6: GLU + leak update: dst = src + leak * val * sigmoid(gate)
// ---------------------------------------------------------------------------
__global__ void k_glu(const float* __restrict__ ybuf, const float* __restrict__ src,
                      float* __restrict__ dst, const float* __restrict__ leakp)
{
    size_t idx = (size_t)blockIdx.x * 256 + threadIdx.x;
    if (idx >= (size_t)4 * 64 * S3) return;
    float leak = fminf(fmaxf(leakp[0], 0.001f), 1000.f);
    size_t b = idx / (64 * S3);
    size_t rem = idx % (64 * S3);
    float val = ybuf[b * 128 * S3 + rem];
    float gate = ybuf[b * 128 * S3 + (size_t)64 * S3 + rem];
    float sig = 1.f / (1.f + expf(-gate));
    dst[idx] = src[idx] + leak * val * sig;
}

// ---------------------------------------------------------------------------
// K8: outc 1x1 conv: f2 (B,193,SP) = outc_w (193,64) @ f1 (B,64,SP) + outc_b
// ---------------------------------------------------------------------------
__global__ __launch_bounds__(256) void k_outc(
    const float* __restrict__ f1, const float* __restrict__ ow,
    const float* __restrict__ ob, float* __restrict__ f2)
{
    const int b = blockIdx.y;
    const int pix0 = blockIdx.x * 32;
    __shared__ float wS[193 * 64];
    __shared__ float bS[193];
    __shared__ float ft[64 * 33];
    const int tid = threadIdx.x;
    for (int i = tid; i < 193 * 64; i += 256) wS[i] = ow[i];
    if (tid < 193) bS[tid] = ob[tid];
    for (int i = tid; i < 64 * 32; i += 256) {
        int c = i >> 5, p = i & 31;
        ft[c * 33 + p] = f1[((size_t)b * 64 + c) * SP + pix0 + p];
    }
    __syncthreads();
    for (int i = tid; i < 193 * 32; i += 256) {
        int o = i >> 5, p = i & 31;
        float acc = bS[o];
        #pragma unroll 8
        for (int k = 0; k < 64; k++) acc += wS[o * 64 + k] * ft[k * 33 + p];
        f2[((size_t)b * 193 + o) * SP + pix0 + p] = acc;
    }
}

// K9a: cf means (one block per (c,b))
__global__ __launch_bounds__(256) void k_cf(const float* __restrict__ f2,
                                            float* __restrict__ state)
{
    int c = blockIdx.x, b = blockIdx.y;
    const float* src = f2 + ((size_t)b * 193 + c) * SP;
    float sum = 0.f;
    for (int i = threadIdx.x; i < SP; i += 256) sum += src[i];
    #pragma unroll
    for (int off = 32; off > 0; off >>= 1) sum += __shfl_down(sum, off);
    __shared__ float red[4];
    if ((threadIdx.x & 63) == 0) red[threadIdx.x >> 6] = sum;
    __syncthreads();
    if (threadIdx.x == 0)
        state[(size_t)b * 32832 + c] = (red[0] + red[1] + red[2] + red[3]) * (1.f / 16384.f);
}

// K9b: cfh / cfw / chw
__global__ void k_state2(const float* __restrict__ f2, float* __restrict__ state)
{
    int id = blockIdx.x * 256 + threadIdx.x;
    if (id >= 4 * 32768) return;
    int b = id >> 15, r = id & 32767;
    float* st = state + (size_t)b * 32832;
    const float* fb = f2 + (size_t)b * 193 * SP;
    if (r < 8192) {
        int c = r >> 7, h = r & 127;
        const float* p = fb + (size_t)(64 + c) * SP + h * 128;
        float sum = 0.f;
        for (int w = 0; w < 128; w++) sum += p[w];
        st[64 + r] = sum * (1.f / 128.f);
    } else if (r < 16384) {
        int rr = r - 8192;
        int c = rr >> 7, w = rr & 127;
        const float* p = fb + (size_t)(128 + c) * SP + w;
        float sum = 0.f;
        for (int h = 0; h < 128; h++) sum += p[h << 7];
        st[8256 + rr] = sum * (1.f / 128.f);
    } else {
        int rr = r - 16384;
        st[16448 + rr] = fb[(size_t)192 * SP + rr];
    }
}

// k-split GEMV with atomics (for the huge l1a_w / l1s_w)
__global__ __launch_bounds__(256) void k_gemv_atomic(
    const float* __restrict__ W, const float* __restrict__ X,
    float* __restrict__ out, int K, int N, int kchunk)
{
    int col = blockIdx.x * 256 + threadIdx.x;
    int k0 = blockIdx.y * kchunk;
    int k1 = min(K, k0 + kchunk);
    if (col >= N) return;
    float a0 = 0.f, a1 = 0.f, a2 = 0.f, a3 = 0.f;
    for (int k = k0; k < k1; k++) {
        float w = W[(size_t)k * N + col];
        a0 += X[k] * w;
        a1 += X[K + k] * w;
        a2 += X[2 * K + k] * w;
        a3 += X[3 * K + k] * w;
    }
    atomicAdd(&out[col], a0);
    atomicAdd(&out[N + col], a1);
    atomicAdd(&out[2 * N + col], a2);
    atomicAdd(&out[3 * N + col], a3);
}

__global__ void k_lrelu_bias(float* __restrict__ z, const float* __restrict__ bias, int N)
{
    int id = blockIdx.x * 256 + threadIdx.x;
    if (id < 4 * N) {
        float v = z[id] + bias[id % N];
        z[id] = v >= 0.f ? v : 0.2f * v;
    }
}

template<int ACT>
__global__ void k_gemv_small(const float* __restrict__ X, const float* __restrict__ W,
                             const float* __restrict__ bias, const float* __restrict__ skip,
                             float* __restrict__ out, int K, int N)
{
    int n = blockIdx.x * 256 + threadIdx.x;
    int b = blockIdx.y;
    if (n >= N) return;
    float acc = bias[n] + (skip ? skip[(size_t)b * N + n] : 0.f);
    const float* x = X + (size_t)b * K;
    for (int k = 0; k < K; k++) acc += x[k] * W[(size_t)k * N + n];
    if (ACT) acc = acc >= 0.f ? acc : 0.2f * acc;
    out[(size_t)b * N + n] = acc;
}

// ---------------------------------------------------------------------------
extern "C" void kernel_launch(void* const* d_in, const int* in_sizes, int n_in,
                              void* d_out, int out_size, void* d_ws, size_t ws_size,
                              hipStream_t stream)
{
    const float* x       = (const float*)d_in[0];
    const float* inj_lat = (const float*)d_in[1];
    const float* in_w    = (const float*)d_in[2];
    const float* in_b    = (const float*)d_in[3];
    const float* rbin_w1 = (const float*)d_in[4];
    const float* rbin_b1 = (const float*)d_in[5];
    const float* rbin_w2 = (const float*)d_in[6];
    const float* rbin_b2 = (const float*)d_in[7];
    const float* leak    = (const float*)d_in[8];
    const float* hyper_w = (const float*)d_in[9];
    const float* hyper_b = (const float*)d_in[10];
    const float* rbout_w1= (const float*)d_in[11];
    const float* rbout_b1= (const float*)d_in[12];
    const float* rbout_w2= (const float*)d_in[13];
    const float* rbout_b2= (const float*)d_in[14];
    const float* outc_w  = (const float*)d_in[15];
    const float* outc_b  = (const float*)d_in[16];
    const float* l1a_w   = (const float*)d_in[17];
    const float* l1a_b   = (const float*)d_in[18];
    const float* l1b_w   = (const float*)d_in[19];
    const float* l1b_b   = (const float*)d_in[20];
    const float* l1s_w   = (const float*)d_in[21];
    const float* l2a_w   = (const float*)d_in[22];
    const float* l2a_b   = (const float*)d_in[23];
    const float* l2b_w   = (const float*)d_in[24];
    const float* l2b_b   = (const float*)d_in[25];
    const float* lat_w   = (const float*)d_in[26];
    const float* lat_b   = (const float*)d_in[27];
    float* out = (float*)d_out;

    // workspace layout (float offsets); total ~59.16M floats = ~237 MB
    float* Wf     = (float*)d_ws;
    float* dp     = Wf + 0;          // 394752
    float* apack  = Wf + 394752;     // 262144
    float* bias3  = Wf + 656896;     // 512
    float* ssum   = Wf + 657408;     // 3584
    float* smean  = Wf + 660992;     // 1792
    float* srstd  = Wf + 662784;     // 1792
    float* carryA = Wf + 664576;     // 4499456
    float* carryB = Wf + 5164032;    // 4499456
    float* hh1    = Wf + 9663488;    // 4499456 (post-scan: f1)
    float* bg3    = Wf + 14162944;   // 35995648 (post-scan: f2,state,z*)
    float* ybuf   = Wf + 50158592;   // 8998912
    float* f1   = hh1;
    float* f2   = bg3;
    float* state = bg3 + 12648448;
    float* z1    = state + 131328;   // 4096
    float* zS    = z1 + 4096;        // 2048
    float* zres1 = zS + 2048;        // 2048
    float* ztmp  = zres1 + 2048;     // 2048
    float* zres2 = ztmp + 2048;      // 2048

    // 1. carry init (zero pad region) + input conv + rb2d
    hipMemsetAsync(carryA, 0, (size_t)4499456 * 4, stream);
    k_rb2d<0><<<dim3(256, 4), 256, 0, stream>>>(x, in_w, in_b, rbin_w1, rbin_b1,
                                                rbin_w2, rbin_b2, carryA);
    // 2. hypernet + weight packing
    k_hyper<<<dim3(386), 256, 0, stream>>>(inj_lat, hyper_w, hyper_b, dp);
    k_apack<<<dim3(1024), 256, 0, stream>>>(dp, apack, bias3);

    // 3. scan (4 steps)
    float* cs = carryA;
    float* cd = carryB;
    for (int step = 0; step < 4; step++) {
        hipMemsetAsync(ssum, 0, (size_t)3584 * 4, stream);
        k_conv<<<dim3(5, 64, 4), 256, 0, stream>>>(cs, bg3, ssum);
        k_stats_fin<<<dim3(7), 256, 0, stream>>>(ssum, smean, srstd);
        // G1: hh1 = lrelu(w1 @ norm(p) + b1)   M=64 K=448
        k_gemm<1, 1><<<dim3(138, 1, 4), 256, 0, stream>>>(
            dp + OFF_W1, (size_t)PTOT, 448,
            bg3 + (size_t)64 * S3, (size_t)512 * S3,
            hh1, (size_t)64 * S3,
            dp + OFF_B1, PTOT, smean, srstd, 448, S3);
        // G2: hh2 = lrelu(w2 @ hh1 + b2) -> bg3 rows 0..63   M=64 K=64
        k_gemm<1, 0><<<dim3(138, 1, 4), 256, 0, stream>>>(
            dp + OFF_W2, (size_t)PTOT, 64,
            hh1, (size_t)64 * S3,
            bg3, (size_t)512 * S3,
            dp + OFF_B2, PTOT, smean, srstd, 64, S3);
        // G3: y = [w3|wsh] @ [hh2; norm(p)] + (b3+bsh)   M=128 K=512
        k_gemm<0, 2><<<dim3(138, 2, 4), 256, 0, stream>>>(
            apack, (size_t)128 * 512, 512,
            bg3, (size_t)512 * S3,
            ybuf, (size_t)128 * S3,
            bias3, 128, smean, srstd, 512, S3);
        // GLU + leaky update
        k_glu<<<dim3(17576), 256, 0, stream>>>(ybuf, cs, cd, leak);
        float* t = cs; cs = cd; cd = t;
    }
    // cs == carryA (final)

    // 4. output rb2d + outc + reductions to state
    k_rb2d<1><<<dim3(256, 4), 256, 0, stream>>>(cs, nullptr, nullptr, rbout_w1,
                                                rbout_b1, rbout_w2, rbout_b2, f1);
    k_outc<<<dim3(512, 4), 256, 0, stream>>>(f1, outc_w, outc_b, f2);
    k_cf<<<dim3(64, 4), 256, 0, stream>>>(f2, state);
    k_state2<<<dim3(512), 256, 0, stream>>>(f2, state);

    // 5. MLP head
    hipMemsetAsync(z1, 0, (size_t)4096 * 4, stream);
    hipMemsetAsync(zS, 0, (size_t)2048 * 4, stream);
    k_gemv_atomic<<<dim3(4, 64), 256, 0, stream>>>(l1a_w, state, z1, 32832, 1024, 513);
    k_gemv_atomic<<<dim3(2, 64), 256, 0, stream>>>(l1s_w, state, zS, 32832, 512, 513);
    k_lrelu_bias<<<dim3(16), 256, 0, stream>>>(z1, l1a_b, 1024);
    k_gemv_small<0><<<dim3(2, 4), 256, 0, stream>>>(z1, l1b_w, l1b_b, zS, zres1, 1024, 512);
    k_gemv_small<1><<<dim3(2, 4), 256, 0, stream>>>(zres1, l2a_w, l2a_b, nullptr, ztmp, 512, 512);
    k_gemv_small<0><<<dim3(2, 4), 256, 0, stream>>>(ztmp, l2b_w, l2b_b, zres1, zres2, 512, 512);
    k_gemv_small<0><<<dim3(2, 4), 256, 0, stream>>>(zres2, lat_w, lat_b, nullptr, out, 512, 512);
    (void)in_sizes; (void)n_in; (void)out_size; (void)ws_size;
}

// Round 2
// 2626.010 us; speedup vs baseline: 2.1289x; 2.1289x over previous
//
#include <hip/hip_runtime.h>
#include <math.h>

#define S3 17576   // 26^3
#define SP 16384   // 128^2
#define PTOT 98688

// dp slice offsets
#define OFF_W1 0
#define OFF_B1 28672
#define OFF_W2 28736
#define OFF_B2 32832
#define OFF_W3 32896
#define OFF_B3 41088
#define OFF_WSH 41216
#define OFF_BSH 98560

typedef unsigned short ushortT;
typedef __attribute__((ext_vector_type(8))) short short8_t;
typedef __attribute__((ext_vector_type(4))) float f32x4;

__device__ __forceinline__ ushortT f2bf(float f) {
    union { float f; unsigned int u; } v; v.f = f;
    unsigned int r = v.u + 0x7fffu + ((v.u >> 16) & 1u);
    return (ushortT)(r >> 16);
}
__device__ __forceinline__ float b2f(ushortT u) {
    union { unsigned int u; float f; } v; v.u = ((unsigned int)u) << 16;
    return v.f;
}

// ---------------------------------------------------------------------------
// K1 / K7: fused 1x1-conv (optional) + rb2d over 64-pixel tiles (fp32)
// ---------------------------------------------------------------------------
template<int MODE>
__global__ __launch_bounds__(256) void k_rb2d(
    const float* __restrict__ src, const float* __restrict__ cw,
    const float* __restrict__ cb, const float* __restrict__ w1,
    const float* __restrict__ b1, const float* __restrict__ w2,
    const float* __restrict__ b2, float* __restrict__ dst)
{
    const int b = blockIdx.y;
    const int pix0 = blockIdx.x * 64;
    __shared__ float wsBuf[4096];
    __shared__ float hA[64 * 65];
    __shared__ float hB[64 * 65];
    __shared__ float xt[3 * 64];
    __shared__ float bias1[64], bias2[64], cbias[64], cwS[192];
    const int tid = threadIdx.x;

    for (int i = tid; i < 4096; i += 256) wsBuf[i] = w1[i];
    if (tid < 64) { bias1[tid] = b1[tid]; bias2[tid] = b2[tid]; }
    if (MODE == 0) {
        if (tid < 192) cwS[tid] = cw[tid];
        if (tid < 64) cbias[tid] = cb[tid];
        for (int i = tid; i < 192; i += 256)
            xt[i] = src[((size_t)b * 3 + (i >> 6)) * SP + pix0 + (i & 63)];
    }
    __syncthreads();
    for (int i = tid; i < 4096; i += 256) {
        int c = i >> 6, p = i & 63;
        float v;
        if (MODE == 0) {
            v = cbias[c] + cwS[c * 3 + 0] * xt[p] + cwS[c * 3 + 1] * xt[64 + p]
                + cwS[c * 3 + 2] * xt[128 + p];
        } else {
            v = src[((size_t)b * 64 + c) * S3 + pix0 + p];
        }
        hA[c * 65 + p] = v;
    }
    __syncthreads();
    for (int i = tid; i < 4096; i += 256) {
        int c = i >> 6, p = i & 63;
        float acc = bias1[c];
        #pragma unroll 8
        for (int k = 0; k < 64; k++) acc += wsBuf[c * 64 + k] * hA[k * 65 + p];
        hB[c * 65 + p] = acc >= 0.f ? acc : 0.2f * acc;
    }
    __syncthreads();
    for (int i = tid; i < 4096; i += 256) wsBuf[i] = w2[i];
    __syncthreads();
    for (int i = tid; i < 4096; i += 256) {
        int c = i >> 6, p = i & 63;
        float acc = bias2[c];
        #pragma unroll 8
        for (int k = 0; k < 64; k++) acc += wsBuf[c * 64 + k] * hB[k * 65 + p];
        acc += hA[c * 65 + p];
        if (MODE == 0) dst[((size_t)b * 64 + c) * S3 + pix0 + p] = acc;
        else           dst[((size_t)b * 64 + c) * SP + pix0 + p] = acc;
    }
}

// ---------------------------------------------------------------------------
// K2: hypernet GEMV
// ---------------------------------------------------------------------------
__global__ __launch_bounds__(256) void k_hyper(
    const float* __restrict__ lat, const float* __restrict__ hw,
    const float* __restrict__ hb, float* __restrict__ dp)
{
    int j = blockIdx.x * 256 + threadIdx.x;
    if (j >= PTOT) return;
    float a0 = hb[j], a1 = a0, a2 = a0, a3 = a0;
    for (int k = 0; k < 512; k++) {
        float w = hw[(size_t)k * PTOT + j];
        a0 += lat[k] * w;
        a1 += lat[512 + k] * w;
        a2 += lat[1024 + k] * w;
        a3 += lat[1536 + k] * w;
    }
    dp[j] = a0;
    dp[PTOT + j] = a1;
    dp[2 * PTOT + j] = a2;
    dp[3 * PTOT + j] = a3;
}

// ---------------------------------------------------------------------------
// weight prep: static (w2) once per call
// ---------------------------------------------------------------------------
__global__ void k_prep_g2(const float* __restrict__ dp, ushortT* __restrict__ Abf2,
                          float* __restrict__ bias2p)
{
    int id = blockIdx.x * 256 + threadIdx.x;
    if (id < 16384) {
        int b = id >> 12, rem = id & 4095;
        Abf2[id] = f2bf(dp[(size_t)b * PTOT + OFF_W2 + rem]);
    }
    if (id < 256) {
        int b = id >> 6, m = id & 63;
        bias2p[id] = dp[(size_t)b * PTOT + OFF_B2 + m];
    }
}

// ---------------------------------------------------------------------------
// per-step weight prep: fold inorm (rstd scale + mean bias shift) into A.
// blocks 0..255: G1 (b,m of w1);  256..767: G3 (b,m of [w3|wsh])
// ---------------------------------------------------------------------------
__global__ __launch_bounds__(256) void k_prep_dyn(
    const float* __restrict__ dp, const float* __restrict__ sm,
    const float* __restrict__ sr, ushortT* __restrict__ Abf1,
    float* __restrict__ bias1p, ushortT* __restrict__ Abf3,
    float* __restrict__ bias3p)
{
    const int blk = blockIdx.x, tid = threadIdx.x;
    float partial = 0.f;
    float baseBias = 0.f;
    float* dst;
    if (blk < 256) {
        int b = blk >> 6, m = blk & 63;
        const float* dpb = dp + (size_t)b * PTOT;
        const float* r = sr + b * 448; const float* mu = sm + b * 448;
        ushortT* arow = Abf1 + ((size_t)b * 64 + m) * 448;
        for (int k = tid; k < 448; k += 256) {
            float v = dpb[OFF_W1 + m * 448 + k] * r[k];
            arow[k] = f2bf(v);
            partial += v * mu[k];
        }
        baseBias = dpb[OFF_B1 + m];
        dst = bias1p + b * 64 + m;
    } else {
        int i = blk - 256; int b = i >> 7, m = i & 127;
        const float* dpb = dp + (size_t)b * PTOT;
        const float* r = sr + b * 448; const float* mu = sm + b * 448;
        ushortT* arow = Abf3 + ((size_t)b * 128 + m) * 512;
        for (int k = tid; k < 512; k += 256) {
            float v;
            if (k < 64) {
                v = dpb[OFF_W3 + m * 64 + k];
            } else {
                v = dpb[OFF_WSH + m * 448 + (k - 64)] * r[k - 64];
                partial += v * mu[k - 64];
            }
            arow[k] = f2bf(v);
        }
        baseBias = dpb[OFF_B3 + m] + dpb[OFF_BSH + m];
        dst = bias3p + b * 128 + m;
    }
    #pragma unroll
    for (int off = 32; off > 0; off >>= 1) partial += __shfl_down(partial, off);
    __shared__ float red[4];
    if ((tid & 63) == 0) red[tid >> 6] = partial;
    __syncthreads();
    if (tid == 0) *dst = baseBias - (red[0] + red[1] + red[2] + red[3]);
}

// ---------------------------------------------------------------------------
// K3: sobel conv (sparse taps) -> packed bf16 features + fp32 stats partials
// PFEAT layout: [b][kg=ch/8][n][8] ushort, ch = 64 + p_row (kg 8..63)
// ---------------------------------------------------------------------------
__global__ __launch_bounds__(256) void k_conv(
    const float* __restrict__ carry, ushortT* __restrict__ pfeat,
    float* __restrict__ ssum)
{
    const int slab = blockIdx.x, c = blockIdx.y, b = blockIdx.z;
    const int d0 = slab * 6;
    __shared__ float L[10 * 900];
    __shared__ float red[4][14];
    const float* src = carry + ((size_t)b * 64 + c) * S3;
    const int tid = threadIdx.x;

    for (int idx = tid; idx < 9000; idx += 256) {
        int pd = idx / 900, rem = idx % 900;
        int ph = rem / 30, pw = rem % 30;
        int d = d0 + pd - 2, h = ph - 2, w = pw - 2;
        float v = 0.f;
        if (d >= 0 && d < 26 && h >= 0 && h < 26 && w >= 0 && w < 26)
            v = src[d * 676 + h * 26 + w];
        L[idx] = v;
    }
    __syncthreads();

    const float r2 = 0.70710678118654752f;
    const float g5[5] = {-1.f, -r2, 0.f, r2, 1.f};
    const float s5[5] = {0.f, r2, 1.f, r2, 0.f};
    float s[7] = {0, 0, 0, 0, 0, 0, 0};
    float q[7] = {0, 0, 0, 0, 0, 0, 0};
    ushortT* pf = pfeat + (size_t)b * 64 * S3 * 8;

    for (int vox = tid; vox < 6 * 676; vox += 256) {
        int dl = vox / 676, rem = vox % 676;
        int d = d0 + dl;
        if (d < 26) {
            int h = rem / 26, w = rem % 26;
            int base = (dl + 2) * 900 + (h + 2) * 30 + (w + 2);
            int sidx = d * 676 + rem;
            float raw = L[base];
            float o1 = L[base + 900] - L[base - 900];
            float o2 = L[base + 30] - L[base - 30];
            float o3 = L[base + 1] - L[base - 1];
            float a5x = 0.f, a5y = 0.f, a5z = 0.f;
            #pragma unroll
            for (int i = 0; i < 5; i++) {
                #pragma unroll
                for (int j = 0; j < 5; j++) {
                    int o = base + (i - 2) * 900 + (j - 2) * 30;
                    float wx = g5[i] * s5[j];
                    float wy = s5[i] * g5[j];
                    float wz = s5[i] * s5[j];
                    if (wx != 0.f || wy != 0.f) {
                        float rw = r2 * L[o - 1] + L[o] + r2 * L[o + 1];
                        a5x += wx * rw;
                        a5y += wy * rw;
                    }
                    if (wz != 0.f) {
                        float gw = -L[o - 2] - r2 * L[o - 1] + r2 * L[o + 1] + L[o + 2];
                        a5z += wz * gw;
                    }
                }
            }
            {
                int ch;
                ch = 64 + c;         pf[((size_t)(ch >> 3) * S3 + sidx) * 8 + (ch & 7)] = f2bf(raw);
                ch = 128 + 3 * c;    pf[((size_t)(ch >> 3) * S3 + sidx) * 8 + (ch & 7)] = f2bf(o1);
                ch = 129 + 3 * c;    pf[((size_t)(ch >> 3) * S3 + sidx) * 8 + (ch & 7)] = f2bf(o2);
                ch = 130 + 3 * c;    pf[((size_t)(ch >> 3) * S3 + sidx) * 8 + (ch & 7)] = f2bf(o3);
                ch = 320 + 3 * c;    pf[((size_t)(ch >> 3) * S3 + sidx) * 8 + (ch & 7)] = f2bf(a5x);
                ch = 321 + 3 * c;    pf[((size_t)(ch >> 3) * S3 + sidx) * 8 + (ch & 7)] = f2bf(a5y);
                ch = 322 + 3 * c;    pf[((size_t)(ch >> 3) * S3 + sidx) * 8 + (ch & 7)] = f2bf(a5z);
            }
            s[0] += raw; q[0] += raw * raw;
            s[1] += o1;  q[1] += o1 * o1;
            s[2] += o2;  q[2] += o2 * o2;
            s[3] += o3;  q[3] += o3 * o3;
            s[4] += a5x; q[4] += a5x * a5x;
            s[5] += a5y; q[5] += a5y * a5y;
            s[6] += a5z; q[6] += a5z * a5z;
        }
    }
    #pragma unroll
    for (int off = 32; off > 0; off >>= 1) {
        #pragma unroll
        for (int i = 0; i < 7; i++) {
            s[i] += __shfl_down(s[i], off);
            q[i] += __shfl_down(q[i], off);
        }
    }
    int wave = tid >> 6, lane = tid & 63;
    if (lane == 0) {
        #pragma unroll
        for (int i = 0; i < 7; i++) { red[wave][i] = s[i]; red[wave][7 + i] = q[i]; }
    }
    __syncthreads();
    if (tid < 14) {
        float t = red[0][tid] + red[1][tid] + red[2][tid] + red[3][tid];
        int slot = tid % 7, isq = tid / 7;
        int ch = (slot == 0) ? c : (slot < 4 ? 64 + 3 * c + (slot - 1)
                                             : 256 + 3 * c + (slot - 4));
        atomicAdd(&ssum[((size_t)b * 448 + ch) * 2 + isq], t);
    }
}

__global__ void k_stats_fin(const float* __restrict__ ssum, float* __restrict__ sm,
                            float* __restrict__ sr)
{
    int i = blockIdx.x * 256 + threadIdx.x;
    if (i < 4 * 448) {
        float su = ssum[i * 2], sq = ssum[i * 2 + 1];
        float m = su * (1.f / (float)S3);
        float v = fmaxf(sq * (1.f / (float)S3) - m * m, 0.f);
        sm[i] = m;
        sr[i] = rsqrtf(v + 1e-5f);
    }
}

// ---------------------------------------------------------------------------
// MFMA bf16 GEMM: C[b] = act(A[b] @ Bfeat[b] + bias[b])
// A: [b][BM][K] bf16 (k-contig), B: packed [b][K/8][S3][8] bf16.
// B-fragments loaded DIRECTLY from global (coalesced dwordx4, read-once);
// A staged in LDS (96B-padded rows), ds_read_b128 fragments.
// 4 waves; BM=64 -> 1x4 wave grid (BN=256); BM=128 -> 2x2 (BN=128).
// Wave tile 64x64: 4x4 16x16x32 MFMAs per K-chunk.
// PACKOUT: 1 -> packed bf16 [kg][S3][8]; 0 -> plain bf16 [m][S3].
// ---------------------------------------------------------------------------
template<int BM, int ACT, int PACKOUT>
__global__ __launch_bounds__(256) void k_mfma(
    const ushortT* __restrict__ Abf, const ushortT* __restrict__ Bpk,
    const float* __restrict__ biasB, ushortT* __restrict__ Cout,
    size_t bStride, size_t cStride, int K)
{
    constexpr int WM = (BM == 128) ? 2 : 1;
    constexpr int BN = (BM == 128) ? 128 : 256;
    const int b = blockIdx.z;
    const int n0 = blockIdx.x * BN;
    const int tid = threadIdx.x;
    const int wid = tid >> 6, lane = tid & 63;
    const int quad = lane >> 4, l16 = lane & 15;
    const int wm = wid % WM, wn = wid / WM;
    const int m0w = wm * 64;
    const int n0w = n0 + wn * 64;

    const ushortT* A = Abf + (size_t)b * BM * K;
    const ushortT* Bp = Bpk + (size_t)b * bStride;

    __shared__ __align__(16) ushortT As[BM * 48];

    f32x4 acc[4][4];
    #pragma unroll
    for (int mt = 0; mt < 4; mt++)
        #pragma unroll
        for (int nt = 0; nt < 4; nt++) acc[mt][nt] = (f32x4)0.f;

    size_t bcol[4];
    #pragma unroll
    for (int nt = 0; nt < 4; nt++) {
        int n = n0w + nt * 16 + l16;
        if (n >= S3) n = S3 - 1;
        bcol[nt] = (size_t)n * 8;
    }
    const size_t quadOff = (size_t)quad * S3 * 8;

    for (int k0 = 0; k0 < K; k0 += 32) {
        // B fragments straight from global: (k0/8 + quad)*S3*8 + n*8
        short8_t bfr[4];
        const ushortT* bchunk = Bp + (size_t)k0 * S3 + quadOff;
        #pragma unroll
        for (int nt = 0; nt < 4; nt++)
            bfr[nt] = *(const short8_t*)(bchunk + bcol[nt]);
        __syncthreads();
        // stage A chunk BMx32 -> LDS (rows padded to 48 elems = 96B)
        #pragma unroll
        for (int i = tid; i < BM * 4; i += 256) {
            int m = i >> 2, c4 = i & 3;
            *(short8_t*)&As[m * 48 + c4 * 8] =
                *(const short8_t*)(A + (size_t)m * K + k0 + c4 * 8);
        }
        __syncthreads();
        short8_t af[4];
        #pragma unroll
        for (int mt = 0; mt < 4; mt++)
            af[mt] = *(const short8_t*)&As[(m0w + mt * 16 + l16) * 48 + quad * 8];
        #pragma unroll
        for (int mt = 0; mt < 4; mt++)
            #pragma unroll
            for (int nt = 0; nt < 4; nt++)
                acc[mt][nt] = __builtin_amdgcn_mfma_f32_16x16x32_bf16(
                    af[mt], bfr[nt], acc[mt][nt], 0, 0, 0);
    }
    // epilogue: C/D layout col=lane&15, row=quad*4+reg
    ushortT* Cb = Cout + (size_t)b * cStride;
    #pragma unroll
    for (int mt = 0; mt < 4; mt++) {
        #pragma unroll
        for (int nt = 0; nt < 4; nt++) {
            int n = n0w + nt * 16 + l16;
            if (n >= S3) continue;
            #pragma unroll
            for (int r = 0; r < 4; r++) {
                int m = m0w + mt * 16 + quad * 4 + r;
                float v = acc[mt][nt][r] + biasB[b * BM + m];
                if (ACT) v = v >= 0.f ? v : 0.2f * v;
                if (PACKOUT)
                    Cb[((size_t)(m >> 3) * S3 + n) * 8 + (m & 7)] = f2bf(v);
                else
                    Cb[(size_t)m * S3 + n] = f2bf(v);
            }
        }
    }
}

// ---------------------------------------------------------------------------
// K6: GLU + leak update (ybuf bf16, carry fp32)
// ---------------------------------------------------------------------------
__global__ void k_glu(const ushortT* __restrict__ ybuf, const float* __restrict__ src,
                      float* __restrict__ dst, const float* __restrict__ leakp)
{
    size_t idx = (size_t)blockIdx.x * 256 + threadIdx.x;
    if (idx >= (size_t)4 * 64 * S3) return;
    float leak = fminf(fmaxf(leakp[0], 0.001f), 1000.f);
    size_t b = idx / (64 * S3);
    size_t rem = idx % (64 * S3);
    float val = b2f(ybuf[b * 128 * S3 + rem]);
    float gate = b2f(ybuf[b * 128 * S3 + (size_t)64 * S3 + rem]);
    float sig = 1.f / (1.f + expf(-gate));
    dst[idx] = src[idx] + leak * val * sig;
}

// ---------------------------------------------------------------------------
// K8: outc 1x1 conv (fp32)
// ---------------------------------------------------------------------------
__global__ __launch_bounds__(256) void k_outc(
    const float* __restrict__ f1, const float* __restrict__ ow,
    const float* __restrict__ ob, float* __restrict__ f2)
{
    const int b = blockIdx.y;
    const int pix0 = blockIdx.x * 32;
    __shared__ float wS[193 * 64];
    __shared__ float bS[193];
    __shared__ float ft[64 * 33];
    const int tid = threadIdx.x;
    for (int i = tid; i < 193 * 64; i += 256) wS[i] = ow[i];
    if (tid < 193) bS[tid] = ob[tid];
    for (int i = tid; i < 64 * 32; i += 256) {
        int c = i >> 5, p = i & 31;
        ft[c * 33 + p] = f1[((size_t)b * 64 + c) * SP + pix0 + p];
    }
    __syncthreads();
    for (int i = tid; i < 193 * 32; i += 256) {
        int o = i >> 5, p = i & 31;
        float acc = bS[o];
        #pragma unroll 8
        for (int k = 0; k < 64; k++) acc += wS[o * 64 + k] * ft[k * 33 + p];
        f2[((size_t)b * 193 + o) * SP + pix0 + p] = acc;
    }
}

__global__ __launch_bounds__(256) void k_cf(const float* __restrict__ f2,
                                            float* __restrict__ state)
{
    int c = blockIdx.x, b = blockIdx.y;
    const float* src = f2 + ((size_t)b * 193 + c) * SP;
    float sum = 0.f;
    for (int i = threadIdx.x; i < SP; i += 256) sum += src[i];
    #pragma unroll
    for (int off = 32; off > 0; off >>= 1) sum += __shfl_down(sum, off);
    __shared__ float red[4];
    if ((threadIdx.x & 63) == 0) red[threadIdx.x >> 6] = sum;
    __syncthreads();
    if (threadIdx.x == 0)
        state[(size_t)b * 32832 + c] = (red[0] + red[1] + red[2] + red[3]) * (1.f / 16384.f);
}

__global__ void k_state2(const float* __restrict__ f2, float* __restrict__ state)
{
    int id = blockIdx.x * 256 + threadIdx.x;
    if (id >= 4 * 32768) return;
    int b = id >> 15, r = id & 32767;
    float* st = state + (size_t)b * 32832;
    const float* fb = f2 + (size_t)b * 193 * SP;
    if (r < 8192) {
        int c = r >> 7, h = r & 127;
        const float* p = fb + (size_t)(64 + c) * SP + h * 128;
        float sum = 0.f;
        for (int w = 0; w < 128; w++) sum += p[w];
        st[64 + r] = sum * (1.f / 128.f);
    } else if (r < 16384) {
        int rr = r - 8192;
        int c = rr >> 7, w = rr & 127;
        const float* p = fb + (size_t)(128 + c) * SP + w;
        float sum = 0.f;
        for (int h = 0; h < 128; h++) sum += p[h << 7];
        st[8256 + rr] = sum * (1.f / 128.f);
    } else {
        int rr = r - 16384;
        st[16448 + rr] = fb[(size_t)192 * SP + rr];
    }
}

__global__ __launch_bounds__(256) void k_gemv_atomic(
    const float* __restrict__ W, const float* __restrict__ X,
    float* __restrict__ out, int K, int N, int kchunk)
{
    int col = blockIdx.x * 256 + threadIdx.x;
    int k0 = blockIdx.y * kchunk;
    int k1 = min(K, k0 + kchunk);
    if (col >= N) return;
    float a0 = 0.f, a1 = 0.f, a2 = 0.f, a3 = 0.f;
    for (int k = k0; k < k1; k++) {
        float w = W[(size_t)k * N + col];
        a0 += X[k] * w;
        a1 += X[K + k] * w;
        a2 += X[2 * K + k] * w;
        a3 += X[3 * K + k] * w;
    }
    atomicAdd(&out[col], a0);
    atomicAdd(&out[N + col], a1);
    atomicAdd(&out[2 * N + col], a2);
    atomicAdd(&out[3 * N + col], a3);
}

__global__ void k_lrelu_bias(float* __restrict__ z, const float* __restrict__ bias, int N)
{
    int id = blockIdx.x * 256 + threadIdx.x;
    if (id < 4 * N) {
        float v = z[id] + bias[id % N];
        z[id] = v >= 0.f ? v : 0.2f * v;
    }
}

template<int ACT>
__global__ void k_gemv_small(const float* __restrict__ X, const float* __restrict__ W,
                             const float* __restrict__ bias, const float* __restrict__ skip,
                             float* __restrict__ out, int K, int N)
{
    int n = blockIdx.x * 256 + threadIdx.x;
    int b = blockIdx.y;
    if (n >= N) return;
    float acc = bias[n] + (skip ? skip[(size_t)b * N + n] : 0.f);
    const float* x = X + (size_t)b * K;
    for (int k = 0; k < K; k++) acc += x[k] * W[(size_t)k * N + n];
    if (ACT) acc = acc >= 0.f ? acc : 0.2f * acc;
    out[(size_t)b * N + n] = acc;
}

// ---------------------------------------------------------------------------
extern "C" void kernel_launch(void* const* d_in, const int* in_sizes, int n_in,
                              void* d_out, int out_size, void* d_ws, size_t ws_size,
                              hipStream_t stream)
{
    const float* x       = (const float*)d_in[0];
    const float* inj_lat = (const float*)d_in[1];
    const float* in_w    = (const float*)d_in[2];
    const float* in_b    = (const float*)d_in[3];
    const float* rbin_w1 = (const float*)d_in[4];
    const float* rbin_b1 = (const float*)d_in[5];
    const float* rbin_w2 = (const float*)d_in[6];
    const float* rbin_b2 = (const float*)d_in[7];
    const float* leak    = (const float*)d_in[8];
    const float* hyper_w = (const float*)d_in[9];
    const float* hyper_b = (const float*)d_in[10];
    const float* rbout_w1= (const float*)d_in[11];
    const float* rbout_b1= (const float*)d_in[12];
    const float* rbout_w2= (const float*)d_in[13];
    const float* rbout_b2= (const float*)d_in[14];
    const float* outc_w  = (const float*)d_in[15];
    const float* outc_b  = (const float*)d_in[16];
    const float* l1a_w   = (const float*)d_in[17];
    const float* l1a_b   = (const float*)d_in[18];
    const float* l1b_w   = (const float*)d_in[19];
    const float* l1b_b   = (const float*)d_in[20];
    const float* l1s_w   = (const float*)d_in[21];
    const float* l2a_w   = (const float*)d_in[22];
    const float* l2a_b   = (const float*)d_in[23];
    const float* l2b_w   = (const float*)d_in[24];
    const float* l2b_b   = (const float*)d_in[25];
    const float* lat_w   = (const float*)d_in[26];
    const float* lat_b   = (const float*)d_in[27];
    float* out = (float*)d_out;

    // ---- workspace layout ----
    float* Wf     = (float*)d_ws;
    float* dp     = Wf + 0;          // 394752
    float* bias1p = Wf + 394752;     // 256
    float* bias2p = Wf + 395008;     // 256
    float* bias3p = Wf + 395264;     // 512
    float* ssum   = Wf + 395776;     // 3584
    float* smean  = Wf + 399360;     // 1792
    float* srstd  = Wf + 401152;     // 1792
    float* carryA = Wf + 402944;     // 4499456
    float* carryB = Wf + 4902400;    // 4499456
    // floats end at 9401856 (16B-aligned: 9401856*4 % 16 == 0)
    ushortT* Wu   = (ushortT*)(Wf + 9401856);
    ushortT* Abf1 = Wu + 0;          // 114688
    ushortT* Abf2 = Wu + 114688;     // 16384
    ushortT* Abf3 = Wu + 131072;     // 262144
    ushortT* PH1  = Wu + 393216;     // 4499456  (4 x 8kg x S3 x 8)
    ushortT* ybuf = Wu + 4892672;    // 8998912  (4 x 128 x S3)
    ushortT* PFEAT= Wu + 13891584;   // 35995648 (4 x 64kg x S3 x 8)
    // ushorts end at 49887232 -> total ws use ~137.4 MB
    // post-scan aliases (regions dead after scan):
    float* f1    = (float*)(Wu + 393216);    // 4.19M floats over PH1+ybuf (27MB)
    float* f2    = (float*)(Wu + 13891584);  // 12.6M floats over PFEAT (72MB)
    float* state = carryB;                   // carryB dead post-scan
    float* z1    = state + 131328;
    float* zS    = z1 + 4096;
    float* zres1 = zS + 2048;
    float* ztmp  = zres1 + 2048;
    float* zres2 = ztmp + 2048;

    // 1. carry init + input conv + rb2d
    hipMemsetAsync(carryA, 0, (size_t)4499456 * 4, stream);
    k_rb2d<0><<<dim3(256, 4), 256, 0, stream>>>(x, in_w, in_b, rbin_w1, rbin_b1,
                                                rbin_w2, rbin_b2, carryA);
    // 2. hypernet + static weight prep
    k_hyper<<<dim3(386), 256, 0, stream>>>(inj_lat, hyper_w, hyper_b, dp);
    k_prep_g2<<<dim3(64), 256, 0, stream>>>(dp, Abf2, bias2p);

    // 3. scan (4 steps)
    float* cs = carryA;
    float* cd = carryB;
    for (int step = 0; step < 4; step++) {
        hipMemsetAsync(ssum, 0, (size_t)3584 * 4, stream);
        k_conv<<<dim3(5, 64, 4), 256, 0, stream>>>(cs, PFEAT, ssum);
        k_stats_fin<<<dim3(7), 256, 0, stream>>>(ssum, smean, srstd);
        k_prep_dyn<<<dim3(768), 256, 0, stream>>>(dp, smean, srstd,
                                                  Abf1, bias1p, Abf3, bias3p);
        // G1: hh1 = lrelu(w1' @ pfeat + b1')   M=64 K=448 -> PH1 packed
        k_mfma<64, 1, 1><<<dim3(69, 1, 4), 256, 0, stream>>>(
            Abf1, PFEAT + (size_t)8 * S3 * 8, bias1p, PH1,
            (size_t)64 * S3 * 8, (size_t)8 * S3 * 8, 448);
        // G2: hh2 = lrelu(w2 @ hh1 + b2)   M=64 K=64 -> PFEAT kg0-7 packed
        k_mfma<64, 1, 1><<<dim3(69, 1, 4), 256, 0, stream>>>(
            Abf2, PH1, bias2p, PFEAT,
            (size_t)8 * S3 * 8, (size_t)64 * S3 * 8, 64);
        // G3: y = [w3|wsh'] @ [hh2;pfeat] + b3'   M=128 K=512 -> ybuf plain
        k_mfma<128, 0, 0><<<dim3(138, 1, 4), 256, 0, stream>>>(
            Abf3, PFEAT, bias3p, ybuf,
            (size_t)64 * S3 * 8, (size_t)128 * S3, 512);
        // GLU + leaky update
        k_glu<<<dim3(17576), 256, 0, stream>>>(ybuf, cs, cd, leak);
        float* t = cs; cs = cd; cd = t;
    }
    // cs == carryA (final)

    // 4. output rb2d + outc + reductions to state
    k_rb2d<1><<<dim3(256, 4), 256, 0, stream>>>(cs, nullptr, nullptr, rbout_w1,
                                                rbout_b1, rbout_w2, rbout_b2, f1);
    k_outc<<<dim3(512, 4), 256, 0, stream>>>(f1, outc_w, outc_b, f2);
    k_cf<<<dim3(64, 4), 256, 0, stream>>>(f2, state);
    k_state2<<<dim3(512), 256, 0, stream>>>(f2, state);

    // 5. MLP head
    hipMemsetAsync(z1, 0, (size_t)4096 * 4, stream);
    hipMemsetAsync(zS, 0, (size_t)2048 * 4, stream);
    k_gemv_atomic<<<dim3(4, 64), 256, 0, stream>>>(l1a_w, state, z1, 32832, 1024, 513);
    k_gemv_atomic<<<dim3(2, 64), 256, 0, stream>>>(l1s_w, state, zS, 32832, 512, 513);
    k_lrelu_bias<<<dim3(16), 256, 0, stream>>>(z1, l1a_b, 1024);
    k_gemv_small<0><<<dim3(2, 4), 256, 0, stream>>>(z1, l1b_w, l1b_b, zS, zres1, 1024, 512);
    k_gemv_small<1><<<dim3(2, 4), 256, 0, stream>>>(zres1, l2a_w, l2a_b, nullptr, ztmp, 512, 512);
    k_gemv_small<0><<<dim3(2, 4), 256, 0, stream>>>(ztmp, l2b_w, l2b_b, zres1, zres2, 512, 512);
    k_gemv_small<0><<<dim3(2, 4), 256, 0, stream>>>(zres2, lat_w, lat_b, nullptr, out, 512, 512);
    (void)in_sizes; (void)n_in; (void)out_size; (void)ws_size;
}

// Round 3
// 1762.087 us; speedup vs baseline: 3.1726x; 1.4903x over previous
//
#include <hip/hip_runtime.h>
#include <math.h>

#define S3 17576   // 26^3
#define SP 16384   // 128^2
#define PTOT 98688

// dp slice offsets
#define OFF_W1 0
#define OFF_B1 28672
#define OFF_W2 28736
#define OFF_B2 32832
#define OFF_W3 32896
#define OFF_B3 41088
#define OFF_WSH 41216
#define OFF_BSH 98560

typedef unsigned short ushortT;
typedef __attribute__((ext_vector_type(8))) short short8_t;
typedef __attribute__((ext_vector_type(4))) float f32x4;

__device__ __forceinline__ ushortT f2bf(float f) {
    union { float f; unsigned int u; } v; v.f = f;
    unsigned int r = v.u + 0x7fffu + ((v.u >> 16) & 1u);
    return (ushortT)(r >> 16);
}
__device__ __forceinline__ float b2f(ushortT u) {
    union { unsigned int u; float f; } v; v.u = ((unsigned int)u) << 16;
    return v.f;
}

// ---------------------------------------------------------------------------
// K1 / K7: fused 1x1-conv (optional) + rb2d over 64-pixel tiles (fp32)
// ---------------------------------------------------------------------------
template<int MODE>
__global__ __launch_bounds__(256) void k_rb2d(
    const float* __restrict__ src, const float* __restrict__ cw,
    const float* __restrict__ cb, const float* __restrict__ w1,
    const float* __restrict__ b1, const float* __restrict__ w2,
    const float* __restrict__ b2, float* __restrict__ dst)
{
    const int b = blockIdx.y;
    const int pix0 = blockIdx.x * 64;
    __shared__ float wsBuf[4096];
    __shared__ float hA[64 * 65];
    __shared__ float hB[64 * 65];
    __shared__ float xt[3 * 64];
    __shared__ float bias1[64], bias2[64], cbias[64], cwS[192];
    const int tid = threadIdx.x;

    for (int i = tid; i < 4096; i += 256) wsBuf[i] = w1[i];
    if (tid < 64) { bias1[tid] = b1[tid]; bias2[tid] = b2[tid]; }
    if (MODE == 0) {
        if (tid < 192) cwS[tid] = cw[tid];
        if (tid < 64) cbias[tid] = cb[tid];
        for (int i = tid; i < 192; i += 256)
            xt[i] = src[((size_t)b * 3 + (i >> 6)) * SP + pix0 + (i & 63)];
    }
    __syncthreads();
    for (int i = tid; i < 4096; i += 256) {
        int c = i >> 6, p = i & 63;
        float v;
        if (MODE == 0) {
            v = cbias[c] + cwS[c * 3 + 0] * xt[p] + cwS[c * 3 + 1] * xt[64 + p]
                + cwS[c * 3 + 2] * xt[128 + p];
        } else {
            v = src[((size_t)b * 64 + c) * S3 + pix0 + p];
        }
        hA[c * 65 + p] = v;
    }
    __syncthreads();
    for (int i = tid; i < 4096; i += 256) {
        int c = i >> 6, p = i & 63;
        float acc = bias1[c];
        #pragma unroll 8
        for (int k = 0; k < 64; k++) acc += wsBuf[c * 64 + k] * hA[k * 65 + p];
        hB[c * 65 + p] = acc >= 0.f ? acc : 0.2f * acc;
    }
    __syncthreads();
    for (int i = tid; i < 4096; i += 256) wsBuf[i] = w2[i];
    __syncthreads();
    for (int i = tid; i < 4096; i += 256) {
        int c = i >> 6, p = i & 63;
        float acc = bias2[c];
        #pragma unroll 8
        for (int k = 0; k < 64; k++) acc += wsBuf[c * 64 + k] * hB[k * 65 + p];
        acc += hA[c * 65 + p];
        if (MODE == 0) dst[((size_t)b * 64 + c) * S3 + pix0 + p] = acc;
        else           dst[((size_t)b * 64 + c) * SP + pix0 + p] = acc;
    }
}

// ---------------------------------------------------------------------------
// K2: hypernet GEMV
// ---------------------------------------------------------------------------
__global__ __launch_bounds__(256) void k_hyper(
    const float* __restrict__ lat, const float* __restrict__ hw,
    const float* __restrict__ hb, float* __restrict__ dp)
{
    int j = blockIdx.x * 256 + threadIdx.x;
    if (j >= PTOT) return;
    float a0 = hb[j], a1 = a0, a2 = a0, a3 = a0;
    for (int k = 0; k < 512; k++) {
        float w = hw[(size_t)k * PTOT + j];
        a0 += lat[k] * w;
        a1 += lat[512 + k] * w;
        a2 += lat[1024 + k] * w;
        a3 += lat[1536 + k] * w;
    }
    dp[j] = a0;
    dp[PTOT + j] = a1;
    dp[2 * PTOT + j] = a2;
    dp[3 * PTOT + j] = a3;
}

// ---------------------------------------------------------------------------
// weight prep: static (w2) once per call
// ---------------------------------------------------------------------------
__global__ void k_prep_g2(const float* __restrict__ dp, ushortT* __restrict__ Abf2,
                          float* __restrict__ bias2p)
{
    int id = blockIdx.x * 256 + threadIdx.x;
    if (id < 16384) {
        int b = id >> 12, rem = id & 4095;
        Abf2[id] = f2bf(dp[(size_t)b * PTOT + OFF_W2 + rem]);
    }
    if (id < 256) {
        int b = id >> 6, m = id & 63;
        bias2p[id] = dp[(size_t)b * PTOT + OFF_B2 + m];
    }
}

// ---------------------------------------------------------------------------
// per-step weight prep: fold inorm (rstd scale + mean bias shift) into A.
// ---------------------------------------------------------------------------
__global__ __launch_bounds__(256) void k_prep_dyn(
    const float* __restrict__ dp, const float* __restrict__ sm,
    const float* __restrict__ sr, ushortT* __restrict__ Abf1,
    float* __restrict__ bias1p, ushortT* __restrict__ Abf3,
    float* __restrict__ bias3p)
{
    const int blk = blockIdx.x, tid = threadIdx.x;
    float partial = 0.f;
    float baseBias = 0.f;
    float* dst;
    if (blk < 256) {
        int b = blk >> 6, m = blk & 63;
        const float* dpb = dp + (size_t)b * PTOT;
        const float* r = sr + b * 448; const float* mu = sm + b * 448;
        ushortT* arow = Abf1 + ((size_t)b * 64 + m) * 448;
        for (int k = tid; k < 448; k += 256) {
            float v = dpb[OFF_W1 + m * 448 + k] * r[k];
            arow[k] = f2bf(v);
            partial += v * mu[k];
        }
        baseBias = dpb[OFF_B1 + m];
        dst = bias1p + b * 64 + m;
    } else {
        int i = blk - 256; int b = i >> 7, m = i & 127;
        const float* dpb = dp + (size_t)b * PTOT;
        const float* r = sr + b * 448; const float* mu = sm + b * 448;
        ushortT* arow = Abf3 + ((size_t)b * 128 + m) * 512;
        for (int k = tid; k < 512; k += 256) {
            float v;
            if (k < 64) {
                v = dpb[OFF_W3 + m * 64 + k];
            } else {
                v = dpb[OFF_WSH + m * 448 + (k - 64)] * r[k - 64];
                partial += v * mu[k - 64];
            }
            arow[k] = f2bf(v);
        }
        baseBias = dpb[OFF_B3 + m] + dpb[OFF_BSH + m];
        dst = bias3p + b * 128 + m;
    }
    #pragma unroll
    for (int off = 32; off > 0; off >>= 1) partial += __shfl_down(partial, off);
    __shared__ float red[4];
    if ((tid & 63) == 0) red[tid >> 6] = partial;
    __syncthreads();
    if (tid == 0) *dst = baseBias - (red[0] + red[1] + red[2] + red[3]);
}

// ---------------------------------------------------------------------------
// K3: sobel conv (sparse taps) -> packed bf16 features + fp32 stats partials
// ---------------------------------------------------------------------------
__global__ __launch_bounds__(256) void k_conv(
    const float* __restrict__ carry, ushortT* __restrict__ pfeat,
    float* __restrict__ ssum)
{
    const int slab = blockIdx.x, c = blockIdx.y, b = blockIdx.z;
    const int d0 = slab * 6;
    __shared__ float L[10 * 900];
    __shared__ float red[4][14];
    const float* src = carry + ((size_t)b * 64 + c) * S3;
    const int tid = threadIdx.x;

    for (int idx = tid; idx < 9000; idx += 256) {
        int pd = idx / 900, rem = idx % 900;
        int ph = rem / 30, pw = rem % 30;
        int d = d0 + pd - 2, h = ph - 2, w = pw - 2;
        float v = 0.f;
        if (d >= 0 && d < 26 && h >= 0 && h < 26 && w >= 0 && w < 26)
            v = src[d * 676 + h * 26 + w];
        L[idx] = v;
    }
    __syncthreads();

    const float r2 = 0.70710678118654752f;
    const float g5[5] = {-1.f, -r2, 0.f, r2, 1.f};
    const float s5[5] = {0.f, r2, 1.f, r2, 0.f};
    float s[7] = {0, 0, 0, 0, 0, 0, 0};
    float q[7] = {0, 0, 0, 0, 0, 0, 0};
    ushortT* pf = pfeat + (size_t)b * 64 * S3 * 8;

    for (int vox = tid; vox < 6 * 676; vox += 256) {
        int dl = vox / 676, rem = vox % 676;
        int d = d0 + dl;
        if (d < 26) {
            int h = rem / 26, w = rem % 26;
            int base = (dl + 2) * 900 + (h + 2) * 30 + (w + 2);
            int sidx = d * 676 + rem;
            float raw = L[base];
            float o1 = L[base + 900] - L[base - 900];
            float o2 = L[base + 30] - L[base - 30];
            float o3 = L[base + 1] - L[base - 1];
            float a5x = 0.f, a5y = 0.f, a5z = 0.f;
            #pragma unroll
            for (int i = 0; i < 5; i++) {
                #pragma unroll
                for (int j = 0; j < 5; j++) {
                    int o = base + (i - 2) * 900 + (j - 2) * 30;
                    float wx = g5[i] * s5[j];
                    float wy = s5[i] * g5[j];
                    float wz = s5[i] * s5[j];
                    if (wx != 0.f || wy != 0.f) {
                        float rw = r2 * L[o - 1] + L[o] + r2 * L[o + 1];
                        a5x += wx * rw;
                        a5y += wy * rw;
                    }
                    if (wz != 0.f) {
                        float gw = -L[o - 2] - r2 * L[o - 1] + r2 * L[o + 1] + L[o + 2];
                        a5z += wz * gw;
                    }
                }
            }
            {
                int ch;
                ch = 64 + c;         pf[((size_t)(ch >> 3) * S3 + sidx) * 8 + (ch & 7)] = f2bf(raw);
                ch = 128 + 3 * c;    pf[((size_t)(ch >> 3) * S3 + sidx) * 8 + (ch & 7)] = f2bf(o1);
                ch = 129 + 3 * c;    pf[((size_t)(ch >> 3) * S3 + sidx) * 8 + (ch & 7)] = f2bf(o2);
                ch = 130 + 3 * c;    pf[((size_t)(ch >> 3) * S3 + sidx) * 8 + (ch & 7)] = f2bf(o3);
                ch = 320 + 3 * c;    pf[((size_t)(ch >> 3) * S3 + sidx) * 8 + (ch & 7)] = f2bf(a5x);
                ch = 321 + 3 * c;    pf[((size_t)(ch >> 3) * S3 + sidx) * 8 + (ch & 7)] = f2bf(a5y);
                ch = 322 + 3 * c;    pf[((size_t)(ch >> 3) * S3 + sidx) * 8 + (ch & 7)] = f2bf(a5z);
            }
            s[0] += raw; q[0] += raw * raw;
            s[1] += o1;  q[1] += o1 * o1;
            s[2] += o2;  q[2] += o2 * o2;
            s[3] += o3;  q[3] += o3 * o3;
            s[4] += a5x; q[4] += a5x * a5x;
            s[5] += a5y; q[5] += a5y * a5y;
            s[6] += a5z; q[6] += a5z * a5z;
        }
    }
    #pragma unroll
    for (int off = 32; off > 0; off >>= 1) {
        #pragma unroll
        for (int i = 0; i < 7; i++) {
            s[i] += __shfl_down(s[i], off);
            q[i] += __shfl_down(q[i], off);
        }
    }
    int wave = tid >> 6, lane = tid & 63;
    if (lane == 0) {
        #pragma unroll
        for (int i = 0; i < 7; i++) { red[wave][i] = s[i]; red[wave][7 + i] = q[i]; }
    }
    __syncthreads();
    if (tid < 14) {
        float t = red[0][tid] + red[1][tid] + red[2][tid] + red[3][tid];
        int slot = tid % 7, isq = tid / 7;
        int ch = (slot == 0) ? c : (slot < 4 ? 64 + 3 * c + (slot - 1)
                                             : 256 + 3 * c + (slot - 4));
        atomicAdd(&ssum[((size_t)b * 448 + ch) * 2 + isq], t);
    }
}

__global__ void k_stats_fin(const float* __restrict__ ssum, float* __restrict__ sm,
                            float* __restrict__ sr)
{
    int i = blockIdx.x * 256 + threadIdx.x;
    if (i < 4 * 448) {
        float su = ssum[i * 2], sq = ssum[i * 2 + 1];
        float m = su * (1.f / (float)S3);
        float v = fmaxf(sq * (1.f / (float)S3) - m * m, 0.f);
        sm[i] = m;
        sr[i] = rsqrtf(v + 1e-5f);
    }
}

// ---------------------------------------------------------------------------
// MFMA bf16 GEMM (see round-2 notes): B direct-from-global, A in LDS.
// ---------------------------------------------------------------------------
template<int BM, int ACT, int PACKOUT>
__global__ __launch_bounds__(256) void k_mfma(
    const ushortT* __restrict__ Abf, const ushortT* __restrict__ Bpk,
    const float* __restrict__ biasB, ushortT* __restrict__ Cout,
    size_t bStride, size_t cStride, int K)
{
    constexpr int WM = (BM == 128) ? 2 : 1;
    constexpr int BN = (BM == 128) ? 128 : 256;
    const int b = blockIdx.z;
    const int n0 = blockIdx.x * BN;
    const int tid = threadIdx.x;
    const int wid = tid >> 6, lane = tid & 63;
    const int quad = lane >> 4, l16 = lane & 15;
    const int wm = wid % WM, wn = wid / WM;
    const int m0w = wm * 64;
    const int n0w = n0 + wn * 64;

    const ushortT* A = Abf + (size_t)b * BM * K;
    const ushortT* Bp = Bpk + (size_t)b * bStride;

    __shared__ __align__(16) ushortT As[BM * 48];

    f32x4 acc[4][4];
    #pragma unroll
    for (int mt = 0; mt < 4; mt++)
        #pragma unroll
        for (int nt = 0; nt < 4; nt++) acc[mt][nt] = (f32x4)0.f;

    size_t bcol[4];
    #pragma unroll
    for (int nt = 0; nt < 4; nt++) {
        int n = n0w + nt * 16 + l16;
        if (n >= S3) n = S3 - 1;
        bcol[nt] = (size_t)n * 8;
    }
    const size_t quadOff = (size_t)quad * S3 * 8;

    for (int k0 = 0; k0 < K; k0 += 32) {
        short8_t bfr[4];
        const ushortT* bchunk = Bp + (size_t)k0 * S3 + quadOff;
        #pragma unroll
        for (int nt = 0; nt < 4; nt++)
            bfr[nt] = *(const short8_t*)(bchunk + bcol[nt]);
        __syncthreads();
        #pragma unroll
        for (int i = tid; i < BM * 4; i += 256) {
            int m = i >> 2, c4 = i & 3;
            *(short8_t*)&As[m * 48 + c4 * 8] =
                *(const short8_t*)(A + (size_t)m * K + k0 + c4 * 8);
        }
        __syncthreads();
        short8_t af[4];
        #pragma unroll
        for (int mt = 0; mt < 4; mt++)
            af[mt] = *(const short8_t*)&As[(m0w + mt * 16 + l16) * 48 + quad * 8];
        #pragma unroll
        for (int mt = 0; mt < 4; mt++)
            #pragma unroll
            for (int nt = 0; nt < 4; nt++)
                acc[mt][nt] = __builtin_amdgcn_mfma_f32_16x16x32_bf16(
                    af[mt], bfr[nt], acc[mt][nt], 0, 0, 0);
    }
    ushortT* Cb = Cout + (size_t)b * cStride;
    #pragma unroll
    for (int mt = 0; mt < 4; mt++) {
        #pragma unroll
        for (int nt = 0; nt < 4; nt++) {
            int n = n0w + nt * 16 + l16;
            if (n >= S3) continue;
            #pragma unroll
            for (int r = 0; r < 4; r++) {
                int m = m0w + mt * 16 + quad * 4 + r;
                float v = acc[mt][nt][r] + biasB[b * BM + m];
                if (ACT) v = v >= 0.f ? v : 0.2f * v;
                if (PACKOUT)
                    Cb[((size_t)(m >> 3) * S3 + n) * 8 + (m & 7)] = f2bf(v);
                else
                    Cb[(size_t)m * S3 + n] = f2bf(v);
            }
        }
    }
}

// ---------------------------------------------------------------------------
// K6: GLU + leak update (ybuf bf16, carry fp32)
// ---------------------------------------------------------------------------
__global__ void k_glu(const ushortT* __restrict__ ybuf, const float* __restrict__ src,
                      float* __restrict__ dst, const float* __restrict__ leakp)
{
    size_t idx = (size_t)blockIdx.x * 256 + threadIdx.x;
    if (idx >= (size_t)4 * 64 * S3) return;
    float leak = fminf(fmaxf(leakp[0], 0.001f), 1000.f);
    size_t b = idx / (64 * S3);
    size_t rem = idx % (64 * S3);
    float val = b2f(ybuf[b * 128 * S3 + rem]);
    float gate = b2f(ybuf[b * 128 * S3 + (size_t)64 * S3 + rem]);
    float sig = 1.f / (1.f + expf(-gate));
    dst[idx] = src[idx] + leak * val * sig;
}

// ---------------------------------------------------------------------------
// K8: outc 1x1 conv (fp32)
// ---------------------------------------------------------------------------
__global__ __launch_bounds__(256) void k_outc(
    const float* __restrict__ f1, const float* __restrict__ ow,
    const float* __restrict__ ob, float* __restrict__ f2)
{
    const int b = blockIdx.y;
    const int pix0 = blockIdx.x * 32;
    __shared__ float wS[193 * 64];
    __shared__ float bS[193];
    __shared__ float ft[64 * 33];
    const int tid = threadIdx.x;
    for (int i = tid; i < 193 * 64; i += 256) wS[i] = ow[i];
    if (tid < 193) bS[tid] = ob[tid];
    for (int i = tid; i < 64 * 32; i += 256) {
        int c = i >> 5, p = i & 31;
        ft[c * 33 + p] = f1[((size_t)b * 64 + c) * SP + pix0 + p];
    }
    __syncthreads();
    for (int i = tid; i < 193 * 32; i += 256) {
        int o = i >> 5, p = i & 31;
        float acc = bS[o];
        #pragma unroll 8
        for (int k = 0; k < 64; k++) acc += wS[o * 64 + k] * ft[k * 33 + p];
        f2[((size_t)b * 193 + o) * SP + pix0 + p] = acc;
    }
}

__global__ __launch_bounds__(256) void k_cf(const float* __restrict__ f2,
                                            float* __restrict__ state)
{
    int c = blockIdx.x, b = blockIdx.y;
    const float* src = f2 + ((size_t)b * 193 + c) * SP;
    float sum = 0.f;
    for (int i = threadIdx.x; i < SP; i += 256) sum += src[i];
    #pragma unroll
    for (int off = 32; off > 0; off >>= 1) sum += __shfl_down(sum, off);
    __shared__ float red[4];
    if ((threadIdx.x & 63) == 0) red[threadIdx.x >> 6] = sum;
    __syncthreads();
    if (threadIdx.x == 0)
        state[(size_t)b * 32832 + c] = (red[0] + red[1] + red[2] + red[3]) * (1.f / 16384.f);
}

__global__ void k_state2(const float* __restrict__ f2, float* __restrict__ state)
{
    int id = blockIdx.x * 256 + threadIdx.x;
    if (id >= 4 * 32768) return;
    int b = id >> 15, r = id & 32767;
    float* st = state + (size_t)b * 32832;
    const float* fb = f2 + (size_t)b * 193 * SP;
    if (r < 8192) {
        int c = r >> 7, h = r & 127;
        const float* p = fb + (size_t)(64 + c) * SP + h * 128;
        float sum = 0.f;
        for (int w = 0; w < 128; w++) sum += p[w];
        st[64 + r] = sum * (1.f / 128.f);
    } else if (r < 16384) {
        int rr = r - 8192;
        int c = rr >> 7, w = rr & 127;
        const float* p = fb + (size_t)(128 + c) * SP + w;
        float sum = 0.f;
        for (int h = 0; h < 128; h++) sum += p[h << 7];
        st[8256 + rr] = sum * (1.f / 128.f);
    } else {
        int rr = r - 16384;
        st[16448 + rr] = fb[(size_t)192 * SP + rr];
    }
}

__global__ __launch_bounds__(256) void k_gemv_atomic(
    const float* __restrict__ W, const float* __restrict__ X,
    float* __restrict__ out, int K, int N, int kchunk)
{
    int col = blockIdx.x * 256 + threadIdx.x;
    int k0 = blockIdx.y * kchunk;
    int k1 = min(K, k0 + kchunk);
    if (col >= N) return;
    float a0 = 0.f, a1 = 0.f, a2 = 0.f, a3 = 0.f;
    for (int k = k0; k < k1; k++) {
        float w = W[(size_t)k * N + col];
        a0 += X[k] * w;
        a1 += X[K + k] * w;
        a2 += X[2 * K + k] * w;
        a3 += X[3 * K + k] * w;
    }
    atomicAdd(&out[col], a0);
    atomicAdd(&out[N + col], a1);
    atomicAdd(&out[2 * N + col], a2);
    atomicAdd(&out[3 * N + col], a3);
}

__global__ void k_lrelu_bias(float* __restrict__ z, const float* __restrict__ bias, int N)
{
    int id = blockIdx.x * 256 + threadIdx.x;
    if (id < 4 * N) {
        float v = z[id] + bias[id % N];
        z[id] = v >= 0.f ? v : 0.2f * v;
    }
}

// ---------------------------------------------------------------------------
// k_mlp: small dense layer, k-split x col-split.
// block = 256 threads = 4 k-lanes x 64 cols; grid (N/64, B).
// X staged to LDS; W reads coalesced (64 consecutive cols per wave);
// unroll 8 -> 8 outstanding global loads per thread.
// ---------------------------------------------------------------------------
template<int ACT>
__global__ __launch_bounds__(256) void k_mlp(
    const float* __restrict__ X, const float* __restrict__ W,
    const float* __restrict__ bias, const float* __restrict__ skip,
    float* __restrict__ out, int K, int N)
{
    const int b = blockIdx.y;
    const int colL = threadIdx.x & 63;
    const int col = blockIdx.x * 64 + colL;
    const int kq = threadIdx.x >> 6;
    __shared__ float xs[1024];
    __shared__ float red[4][64];
    const float* x = X + (size_t)b * K;
    for (int i = threadIdx.x; i < K; i += 256) xs[i] = x[i];
    __syncthreads();
    float acc = 0.f;
    #pragma unroll 8
    for (int k = kq; k < K; k += 4)
        acc += xs[k] * W[(size_t)k * N + col];
    red[kq][colL] = acc;
    __syncthreads();
    if (kq == 0) {
        float v = red[0][colL] + red[1][colL] + red[2][colL] + red[3][colL]
                + bias[col] + (skip ? skip[(size_t)b * N + col] : 0.f);
        if (ACT) v = v >= 0.f ? v : 0.2f * v;
        out[(size_t)b * N + col] = v;
    }
}

// ---------------------------------------------------------------------------
extern "C" void kernel_launch(void* const* d_in, const int* in_sizes, int n_in,
                              void* d_out, int out_size, void* d_ws, size_t ws_size,
                              hipStream_t stream)
{
    const float* x       = (const float*)d_in[0];
    const float* inj_lat = (const float*)d_in[1];
    const float* in_w    = (const float*)d_in[2];
    const float* in_b    = (const float*)d_in[3];
    const float* rbin_w1 = (const float*)d_in[4];
    const float* rbin_b1 = (const float*)d_in[5];
    const float* rbin_w2 = (const float*)d_in[6];
    const float* rbin_b2 = (const float*)d_in[7];
    const float* leak    = (const float*)d_in[8];
    const float* hyper_w = (const float*)d_in[9];
    const float* hyper_b = (const float*)d_in[10];
    const float* rbout_w1= (const float*)d_in[11];
    const float* rbout_b1= (const float*)d_in[12];
    const float* rbout_w2= (const float*)d_in[13];
    const float* rbout_b2= (const float*)d_in[14];
    const float* outc_w  = (const float*)d_in[15];
    const float* outc_b  = (const float*)d_in[16];
    const float* l1a_w   = (const float*)d_in[17];
    const float* l1a_b   = (const float*)d_in[18];
    const float* l1b_w   = (const float*)d_in[19];
    const float* l1b_b   = (const float*)d_in[20];
    const float* l1s_w   = (const float*)d_in[21];
    const float* l2a_w   = (const float*)d_in[22];
    const float* l2a_b   = (const float*)d_in[23];
    const float* l2b_w   = (const float*)d_in[24];
    const float* l2b_b   = (const float*)d_in[25];
    const float* lat_w   = (const float*)d_in[26];
    const float* lat_b   = (const float*)d_in[27];
    float* out = (float*)d_out;

    // ---- workspace layout ----
    float* Wf     = (float*)d_ws;
    float* dp     = Wf + 0;          // 394752
    float* bias1p = Wf + 394752;     // 256
    float* bias2p = Wf + 395008;     // 256
    float* bias3p = Wf + 395264;     // 512
    float* ssum   = Wf + 395776;     // 3584
    float* smean  = Wf + 399360;     // 1792
    float* srstd  = Wf + 401152;     // 1792
    float* carryA = Wf + 402944;     // 4499456
    float* carryB = Wf + 4902400;    // 4499456
    ushortT* Wu   = (ushortT*)(Wf + 9401856);
    ushortT* Abf1 = Wu + 0;          // 114688
    ushortT* Abf2 = Wu + 114688;     // 16384
    ushortT* Abf3 = Wu + 131072;     // 262144
    ushortT* PH1  = Wu + 393216;     // 4499456
    ushortT* ybuf = Wu + 4892672;    // 8998912
    ushortT* PFEAT= Wu + 13891584;   // 35995648
    // post-scan aliases:
    float* f1    = (float*)(Wu + 393216);
    float* f2    = (float*)(Wu + 13891584);
    float* state = carryB;
    float* z1    = state + 131328;
    float* zS    = z1 + 4096;
    float* zres1 = zS + 2048;
    float* ztmp  = zres1 + 2048;
    float* zres2 = ztmp + 2048;

    // 1. carry init + input conv + rb2d
    hipMemsetAsync(carryA, 0, (size_t)4499456 * 4, stream);
    k_rb2d<0><<<dim3(256, 4), 256, 0, stream>>>(x, in_w, in_b, rbin_w1, rbin_b1,
                                                rbin_w2, rbin_b2, carryA);
    // 2. hypernet + static weight prep
    k_hyper<<<dim3(386), 256, 0, stream>>>(inj_lat, hyper_w, hyper_b, dp);
    k_prep_g2<<<dim3(64), 256, 0, stream>>>(dp, Abf2, bias2p);

    // 3. scan (4 steps)
    float* cs = carryA;
    float* cd = carryB;
    for (int step = 0; step < 4; step++) {
        hipMemsetAsync(ssum, 0, (size_t)3584 * 4, stream);
        k_conv<<<dim3(5, 64, 4), 256, 0, stream>>>(cs, PFEAT, ssum);
        k_stats_fin<<<dim3(7), 256, 0, stream>>>(ssum, smean, srstd);
        k_prep_dyn<<<dim3(768), 256, 0, stream>>>(dp, smean, srstd,
                                                  Abf1, bias1p, Abf3, bias3p);
        k_mfma<64, 1, 1><<<dim3(69, 1, 4), 256, 0, stream>>>(
            Abf1, PFEAT + (size_t)8 * S3 * 8, bias1p, PH1,
            (size_t)64 * S3 * 8, (size_t)8 * S3 * 8, 448);
        k_mfma<64, 1, 1><<<dim3(69, 1, 4), 256, 0, stream>>>(
            Abf2, PH1, bias2p, PFEAT,
            (size_t)8 * S3 * 8, (size_t)64 * S3 * 8, 64);
        k_mfma<128, 0, 0><<<dim3(138, 1, 4), 256, 0, stream>>>(
            Abf3, PFEAT, bias3p, ybuf,
            (size_t)64 * S3 * 8, (size_t)128 * S3, 512);
        k_glu<<<dim3(17576), 256, 0, stream>>>(ybuf, cs, cd, leak);
        float* t = cs; cs = cd; cd = t;
    }
    // cs == carryA (final)

    // 4. output rb2d + outc + reductions to state
    k_rb2d<1><<<dim3(256, 4), 256, 0, stream>>>(cs, nullptr, nullptr, rbout_w1,
                                                rbout_b1, rbout_w2, rbout_b2, f1);
    k_outc<<<dim3(512, 4), 256, 0, stream>>>(f1, outc_w, outc_b, f2);
    k_cf<<<dim3(64, 4), 256, 0, stream>>>(f2, state);
    k_state2<<<dim3(512), 256, 0, stream>>>(f2, state);

    // 5. MLP head
    hipMemsetAsync(z1, 0, (size_t)4096 * 4, stream);
    hipMemsetAsync(zS, 0, (size_t)2048 * 4, stream);
    k_gemv_atomic<<<dim3(4, 64), 256, 0, stream>>>(l1a_w, state, z1, 32832, 1024, 513);
    k_gemv_atomic<<<dim3(2, 64), 256, 0, stream>>>(l1s_w, state, zS, 32832, 512, 513);
    k_lrelu_bias<<<dim3(16), 256, 0, stream>>>(z1, l1a_b, 1024);
    k_mlp<0><<<dim3(8, 4), 256, 0, stream>>>(z1, l1b_w, l1b_b, zS, zres1, 1024, 512);
    k_mlp<1><<<dim3(8, 4), 256, 0, stream>>>(zres1, l2a_w, l2a_b, nullptr, ztmp, 512, 512);
    k_mlp<0><<<dim3(8, 4), 256, 0, stream>>>(ztmp, l2b_w, l2b_b, zres1, zres2, 512, 512);
    k_mlp<0><<<dim3(8, 4), 256, 0, stream>>>(zres2, lat_w, lat_b, nullptr, out, 512, 512);
    (void)in_sizes; (void)n_in; (void)out_size; (void)ws_size;
}

// Round 4
// 1459.756 us; speedup vs baseline: 3.8297x; 1.2071x over previous
//
#include <hip/hip_runtime.h>
#include <math.h>

#define S3 17576   // 26^3
#define SP 16384   // 128^2
#define PTOT 98688

// dp slice offsets
#define OFF_W1 0
#define OFF_B1 28672
#define OFF_W2 28736
#define OFF_B2 32832
#define OFF_W3 32896
#define OFF_B3 41088
#define OFF_WSH 41216
#define OFF_BSH 98560

typedef unsigned short ushortT;
typedef __attribute__((ext_vector_type(8))) short short8_t;
typedef __attribute__((ext_vector_type(4))) float f32x4;

__device__ __forceinline__ ushortT f2bf(float f) {
    union { float f; unsigned int u; } v; v.f = f;
    unsigned int r = v.u + 0x7fffu + ((v.u >> 16) & 1u);
    return (ushortT)(r >> 16);
}
__device__ __forceinline__ float b2f(ushortT u) {
    union { unsigned int u; float f; } v; v.u = ((unsigned int)u) << 16;
    return v.f;
}

// ---------------------------------------------------------------------------
// K1 / K7: fused 1x1-conv (optional) + rb2d over 64-pixel tiles (fp32)
// ---------------------------------------------------------------------------
template<int MODE>
__global__ __launch_bounds__(256) void k_rb2d(
    const float* __restrict__ src, const float* __restrict__ cw,
    const float* __restrict__ cb, const float* __restrict__ w1,
    const float* __restrict__ b1, const float* __restrict__ w2,
    const float* __restrict__ b2, float* __restrict__ dst)
{
    const int b = blockIdx.y;
    const int pix0 = blockIdx.x * 64;
    __shared__ float wsBuf[4096];
    __shared__ float hA[64 * 65];
    __shared__ float hB[64 * 65];
    __shared__ float xt[3 * 64];
    __shared__ float bias1[64], bias2[64], cbias[64], cwS[192];
    const int tid = threadIdx.x;

    for (int i = tid; i < 4096; i += 256) wsBuf[i] = w1[i];
    if (tid < 64) { bias1[tid] = b1[tid]; bias2[tid] = b2[tid]; }
    if (MODE == 0) {
        if (tid < 192) cwS[tid] = cw[tid];
        if (tid < 64) cbias[tid] = cb[tid];
        for (int i = tid; i < 192; i += 256)
            xt[i] = src[((size_t)b * 3 + (i >> 6)) * SP + pix0 + (i & 63)];
    }
    __syncthreads();
    for (int i = tid; i < 4096; i += 256) {
        int c = i >> 6, p = i & 63;
        float v;
        if (MODE == 0) {
            v = cbias[c] + cwS[c * 3 + 0] * xt[p] + cwS[c * 3 + 1] * xt[64 + p]
                + cwS[c * 3 + 2] * xt[128 + p];
        } else {
            v = src[((size_t)b * 64 + c) * S3 + pix0 + p];
        }
        hA[c * 65 + p] = v;
    }
    __syncthreads();
    for (int i = tid; i < 4096; i += 256) {
        int c = i >> 6, p = i & 63;
        float acc = bias1[c];
        #pragma unroll 8
        for (int k = 0; k < 64; k++) acc += wsBuf[c * 64 + k] * hA[k * 65 + p];
        hB[c * 65 + p] = acc >= 0.f ? acc : 0.2f * acc;
    }
    __syncthreads();
    for (int i = tid; i < 4096; i += 256) wsBuf[i] = w2[i];
    __syncthreads();
    for (int i = tid; i < 4096; i += 256) {
        int c = i >> 6, p = i & 63;
        float acc = bias2[c];
        #pragma unroll 8
        for (int k = 0; k < 64; k++) acc += wsBuf[c * 64 + k] * hB[k * 65 + p];
        acc += hA[c * 65 + p];
        if (MODE == 0) dst[((size_t)b * 64 + c) * S3 + pix0 + p] = acc;
        else           dst[((size_t)b * 64 + c) * SP + pix0 + p] = acc;
    }
}

// ---------------------------------------------------------------------------
// K2: hypernet GEMV — unroll 8 for in-flight loads (was latency-serialized)
// ---------------------------------------------------------------------------
__global__ __launch_bounds__(256) void k_hyper(
    const float* __restrict__ lat, const float* __restrict__ hw,
    const float* __restrict__ hb, float* __restrict__ dp)
{
    int j = blockIdx.x * 256 + threadIdx.x;
    if (j >= PTOT) return;
    float a0 = hb[j], a1 = a0, a2 = a0, a3 = a0;
    #pragma unroll 8
    for (int k = 0; k < 512; k++) {
        float w = hw[(size_t)k * PTOT + j];
        a0 += lat[k] * w;
        a1 += lat[512 + k] * w;
        a2 += lat[1024 + k] * w;
        a3 += lat[1536 + k] * w;
    }
    dp[j] = a0;
    dp[PTOT + j] = a1;
    dp[2 * PTOT + j] = a2;
    dp[3 * PTOT + j] = a3;
}

// ---------------------------------------------------------------------------
// weight prep: static (w2) once per call
// ---------------------------------------------------------------------------
__global__ void k_prep_g2(const float* __restrict__ dp, ushortT* __restrict__ Abf2,
                          float* __restrict__ bias2p)
{
    int id = blockIdx.x * 256 + threadIdx.x;
    if (id < 16384) {
        int b = id >> 12, rem = id & 4095;
        Abf2[id] = f2bf(dp[(size_t)b * PTOT + OFF_W2 + rem]);
    }
    if (id < 256) {
        int b = id >> 6, m = id & 63;
        bias2p[id] = dp[(size_t)b * PTOT + OFF_B2 + m];
    }
}

// ---------------------------------------------------------------------------
// per-step weight prep: fold inorm (rstd scale + mean bias shift) into A.
// ---------------------------------------------------------------------------
__global__ __launch_bounds__(256) void k_prep_dyn(
    const float* __restrict__ dp, const float* __restrict__ sm,
    const float* __restrict__ sr, ushortT* __restrict__ Abf1,
    float* __restrict__ bias1p, ushortT* __restrict__ Abf3,
    float* __restrict__ bias3p)
{
    const int blk = blockIdx.x, tid = threadIdx.x;
    float partial = 0.f;
    float baseBias = 0.f;
    float* dst;
    if (blk < 256) {
        int b = blk >> 6, m = blk & 63;
        const float* dpb = dp + (size_t)b * PTOT;
        const float* r = sr + b * 448; const float* mu = sm + b * 448;
        ushortT* arow = Abf1 + ((size_t)b * 64 + m) * 448;
        for (int k = tid; k < 448; k += 256) {
            float v = dpb[OFF_W1 + m * 448 + k] * r[k];
            arow[k] = f2bf(v);
            partial += v * mu[k];
        }
        baseBias = dpb[OFF_B1 + m];
        dst = bias1p + b * 64 + m;
    } else {
        int i = blk - 256; int b = i >> 7, m = i & 127;
        const float* dpb = dp + (size_t)b * PTOT;
        const float* r = sr + b * 448; const float* mu = sm + b * 448;
        ushortT* arow = Abf3 + ((size_t)b * 128 + m) * 512;
        for (int k = tid; k < 512; k += 256) {
            float v;
            if (k < 64) {
                v = dpb[OFF_W3 + m * 64 + k];
            } else {
                v = dpb[OFF_WSH + m * 448 + (k - 64)] * r[k - 64];
                partial += v * mu[k - 64];
            }
            arow[k] = f2bf(v);
        }
        baseBias = dpb[OFF_B3 + m] + dpb[OFF_BSH + m];
        dst = bias3p + b * 128 + m;
    }
    #pragma unroll
    for (int off = 32; off > 0; off >>= 1) partial += __shfl_down(partial, off);
    __shared__ float red[4];
    if ((tid & 63) == 0) red[tid >> 6] = partial;
    __syncthreads();
    if (tid == 0) *dst = baseBias - (red[0] + red[1] + red[2] + red[3]);
}

// ---------------------------------------------------------------------------
// K3: sobel conv (sparse taps) -> packed bf16 features + fp32 stats partials
// ---------------------------------------------------------------------------
__global__ __launch_bounds__(256) void k_conv(
    const float* __restrict__ carry, ushortT* __restrict__ pfeat,
    float* __restrict__ ssum)
{
    const int slab = blockIdx.x, c = blockIdx.y, b = blockIdx.z;
    const int d0 = slab * 6;
    __shared__ float L[10 * 900];
    __shared__ float red[4][14];
    const float* src = carry + ((size_t)b * 64 + c) * S3;
    const int tid = threadIdx.x;

    for (int idx = tid; idx < 9000; idx += 256) {
        int pd = idx / 900, rem = idx % 900;
        int ph = rem / 30, pw = rem % 30;
        int d = d0 + pd - 2, h = ph - 2, w = pw - 2;
        float v = 0.f;
        if (d >= 0 && d < 26 && h >= 0 && h < 26 && w >= 0 && w < 26)
            v = src[d * 676 + h * 26 + w];
        L[idx] = v;
    }
    __syncthreads();

    const float r2 = 0.70710678118654752f;
    const float g5[5] = {-1.f, -r2, 0.f, r2, 1.f};
    const float s5[5] = {0.f, r2, 1.f, r2, 0.f};
    float s[7] = {0, 0, 0, 0, 0, 0, 0};
    float q[7] = {0, 0, 0, 0, 0, 0, 0};
    ushortT* pf = pfeat + (size_t)b * 64 * S3 * 8;

    for (int vox = tid; vox < 6 * 676; vox += 256) {
        int dl = vox / 676, rem = vox % 676;
        int d = d0 + dl;
        if (d < 26) {
            int h = rem / 26, w = rem % 26;
            int base = (dl + 2) * 900 + (h + 2) * 30 + (w + 2);
            int sidx = d * 676 + rem;
            float raw = L[base];
            float o1 = L[base + 900] - L[base - 900];
            float o2 = L[base + 30] - L[base - 30];
            float o3 = L[base + 1] - L[base - 1];
            float a5x = 0.f, a5y = 0.f, a5z = 0.f;
            #pragma unroll
            for (int i = 0; i < 5; i++) {
                #pragma unroll
                for (int j = 0; j < 5; j++) {
                    int o = base + (i - 2) * 900 + (j - 2) * 30;
                    float wx = g5[i] * s5[j];
                    float wy = s5[i] * g5[j];
                    float wz = s5[i] * s5[j];
                    if (wx != 0.f || wy != 0.f) {
                        float rw = r2 * L[o - 1] + L[o] + r2 * L[o + 1];
                        a5x += wx * rw;
                        a5y += wy * rw;
                    }
                    if (wz != 0.f) {
                        float gw = -L[o - 2] - r2 * L[o - 1] + r2 * L[o + 1] + L[o + 2];
                        a5z += wz * gw;
                    }
                }
            }
            {
                int ch;
                ch = 64 + c;         pf[((size_t)(ch >> 3) * S3 + sidx) * 8 + (ch & 7)] = f2bf(raw);
                ch = 128 + 3 * c;    pf[((size_t)(ch >> 3) * S3 + sidx) * 8 + (ch & 7)] = f2bf(o1);
                ch = 129 + 3 * c;    pf[((size_t)(ch >> 3) * S3 + sidx) * 8 + (ch & 7)] = f2bf(o2);
                ch = 130 + 3 * c;    pf[((size_t)(ch >> 3) * S3 + sidx) * 8 + (ch & 7)] = f2bf(o3);
                ch = 320 + 3 * c;    pf[((size_t)(ch >> 3) * S3 + sidx) * 8 + (ch & 7)] = f2bf(a5x);
                ch = 321 + 3 * c;    pf[((size_t)(ch >> 3) * S3 + sidx) * 8 + (ch & 7)] = f2bf(a5y);
                ch = 322 + 3 * c;    pf[((size_t)(ch >> 3) * S3 + sidx) * 8 + (ch & 7)] = f2bf(a5z);
            }
            s[0] += raw; q[0] += raw * raw;
            s[1] += o1;  q[1] += o1 * o1;
            s[2] += o2;  q[2] += o2 * o2;
            s[3] += o3;  q[3] += o3 * o3;
            s[4] += a5x; q[4] += a5x * a5x;
            s[5] += a5y; q[5] += a5y * a5y;
            s[6] += a5z; q[6] += a5z * a5z;
        }
    }
    #pragma unroll
    for (int off = 32; off > 0; off >>= 1) {
        #pragma unroll
        for (int i = 0; i < 7; i++) {
            s[i] += __shfl_down(s[i], off);
            q[i] += __shfl_down(q[i], off);
        }
    }
    int wave = tid >> 6, lane = tid & 63;
    if (lane == 0) {
        #pragma unroll
        for (int i = 0; i < 7; i++) { red[wave][i] = s[i]; red[wave][7 + i] = q[i]; }
    }
    __syncthreads();
    if (tid < 14) {
        float t = red[0][tid] + red[1][tid] + red[2][tid] + red[3][tid];
        int slot = tid % 7, isq = tid / 7;
        int ch = (slot == 0) ? c : (slot < 4 ? 64 + 3 * c + (slot - 1)
                                             : 256 + 3 * c + (slot - 4));
        atomicAdd(&ssum[((size_t)b * 448 + ch) * 2 + isq], t);
    }
}

__global__ void k_stats_fin(const float* __restrict__ ssum, float* __restrict__ sm,
                            float* __restrict__ sr)
{
    int i = blockIdx.x * 256 + threadIdx.x;
    if (i < 4 * 448) {
        float su = ssum[i * 2], sq = ssum[i * 2 + 1];
        float m = su * (1.f / (float)S3);
        float v = fmaxf(sq * (1.f / (float)S3) - m * m, 0.f);
        sm[i] = m;
        sr[i] = rsqrtf(v + 1e-5f);
    }
}

// ---------------------------------------------------------------------------
// MFMA bf16 GEMM: B direct-from-global (packed [kg][n][8]), A in LDS.
// ---------------------------------------------------------------------------
template<int BM, int ACT, int PACKOUT>
__global__ __launch_bounds__(256) void k_mfma(
    const ushortT* __restrict__ Abf, const ushortT* __restrict__ Bpk,
    const float* __restrict__ biasB, ushortT* __restrict__ Cout,
    size_t bStride, size_t cStride, int K)
{
    constexpr int WM = (BM == 128) ? 2 : 1;
    constexpr int BN = (BM == 128) ? 128 : 256;
    const int b = blockIdx.z;
    const int n0 = blockIdx.x * BN;
    const int tid = threadIdx.x;
    const int wid = tid >> 6, lane = tid & 63;
    const int quad = lane >> 4, l16 = lane & 15;
    const int wm = wid % WM, wn = wid / WM;
    const int m0w = wm * 64;
    const int n0w = n0 + wn * 64;

    const ushortT* A = Abf + (size_t)b * BM * K;
    const ushortT* Bp = Bpk + (size_t)b * bStride;

    __shared__ __align__(16) ushortT As[BM * 48];

    f32x4 acc[4][4];
    #pragma unroll
    for (int mt = 0; mt < 4; mt++)
        #pragma unroll
        for (int nt = 0; nt < 4; nt++) acc[mt][nt] = (f32x4)0.f;

    size_t bcol[4];
    #pragma unroll
    for (int nt = 0; nt < 4; nt++) {
        int n = n0w + nt * 16 + l16;
        if (n >= S3) n = S3 - 1;
        bcol[nt] = (size_t)n * 8;
    }
    const size_t quadOff = (size_t)quad * S3 * 8;

    for (int k0 = 0; k0 < K; k0 += 32) {
        short8_t bfr[4];
        const ushortT* bchunk = Bp + (size_t)k0 * S3 + quadOff;
        #pragma unroll
        for (int nt = 0; nt < 4; nt++)
            bfr[nt] = *(const short8_t*)(bchunk + bcol[nt]);
        __syncthreads();
        #pragma unroll
        for (int i = tid; i < BM * 4; i += 256) {
            int m = i >> 2, c4 = i & 3;
            *(short8_t*)&As[m * 48 + c4 * 8] =
                *(const short8_t*)(A + (size_t)m * K + k0 + c4 * 8);
        }
        __syncthreads();
        short8_t af[4];
        #pragma unroll
        for (int mt = 0; mt < 4; mt++)
            af[mt] = *(const short8_t*)&As[(m0w + mt * 16 + l16) * 48 + quad * 8];
        #pragma unroll
        for (int mt = 0; mt < 4; mt++)
            #pragma unroll
            for (int nt = 0; nt < 4; nt++)
                acc[mt][nt] = __builtin_amdgcn_mfma_f32_16x16x32_bf16(
                    af[mt], bfr[nt], acc[mt][nt], 0, 0, 0);
    }
    ushortT* Cb = Cout + (size_t)b * cStride;
    #pragma unroll
    for (int mt = 0; mt < 4; mt++) {
        #pragma unroll
        for (int nt = 0; nt < 4; nt++) {
            int n = n0w + nt * 16 + l16;
            if (n >= S3) continue;
            #pragma unroll
            for (int r = 0; r < 4; r++) {
                int m = m0w + mt * 16 + quad * 4 + r;
                float v = acc[mt][nt][r] + biasB[b * BM + m];
                if (ACT) v = v >= 0.f ? v : 0.2f * v;
                if (PACKOUT)
                    Cb[((size_t)(m >> 3) * S3 + n) * 8 + (m & 7)] = f2bf(v);
                else
                    Cb[(size_t)m * S3 + n] = f2bf(v);
            }
        }
    }
}

// ---------------------------------------------------------------------------
// K6: GLU + leak update (ybuf bf16, carry fp32)
// ---------------------------------------------------------------------------
__global__ void k_glu(const ushortT* __restrict__ ybuf, const float* __restrict__ src,
                      float* __restrict__ dst, const float* __restrict__ leakp)
{
    size_t idx = (size_t)blockIdx.x * 256 + threadIdx.x;
    if (idx >= (size_t)4 * 64 * S3) return;
    float leak = fminf(fmaxf(leakp[0], 0.001f), 1000.f);
    size_t b = idx / (64 * S3);
    size_t rem = idx % (64 * S3);
    float val = b2f(ybuf[b * 128 * S3 + rem]);
    float gate = b2f(ybuf[b * 128 * S3 + (size_t)64 * S3 + rem]);
    float sig = 1.f / (1.f + expf(-gate));
    dst[idx] = src[idx] + leak * val * sig;
}

// ---------------------------------------------------------------------------
// K8: outc 1x1 conv (fp32)
// ---------------------------------------------------------------------------
__global__ __launch_bounds__(256) void k_outc(
    const float* __restrict__ f1, const float* __restrict__ ow,
    const float* __restrict__ ob, float* __restrict__ f2)
{
    const int b = blockIdx.y;
    const int pix0 = blockIdx.x * 32;
    __shared__ float wS[193 * 64];
    __shared__ float bS[193];
    __shared__ float ft[64 * 33];
    const int tid = threadIdx.x;
    for (int i = tid; i < 193 * 64; i += 256) wS[i] = ow[i];
    if (tid < 193) bS[tid] = ob[tid];
    for (int i = tid; i < 64 * 32; i += 256) {
        int c = i >> 5, p = i & 31;
        ft[c * 33 + p] = f1[((size_t)b * 64 + c) * SP + pix0 + p];
    }
    __syncthreads();
    for (int i = tid; i < 193 * 32; i += 256) {
        int o = i >> 5, p = i & 31;
        float acc = bS[o];
        #pragma unroll 8
        for (int k = 0; k < 64; k++) acc += wS[o * 64 + k] * ft[k * 33 + p];
        f2[((size_t)b * 193 + o) * SP + pix0 + p] = acc;
    }
}

__global__ __launch_bounds__(256) void k_cf(const float* __restrict__ f2,
                                            float* __restrict__ state)
{
    int c = blockIdx.x, b = blockIdx.y;
    const float* src = f2 + ((size_t)b * 193 + c) * SP;
    float sum = 0.f;
    for (int i = threadIdx.x; i < SP; i += 256) sum += src[i];
    #pragma unroll
    for (int off = 32; off > 0; off >>= 1) sum += __shfl_down(sum, off);
    __shared__ float red[4];
    if ((threadIdx.x & 63) == 0) red[threadIdx.x >> 6] = sum;
    __syncthreads();
    if (threadIdx.x == 0)
        state[(size_t)b * 32832 + c] = (red[0] + red[1] + red[2] + red[3]) * (1.f / 16384.f);
}

__global__ void k_state2(const float* __restrict__ f2, float* __restrict__ state)
{
    int id = blockIdx.x * 256 + threadIdx.x;
    if (id >= 4 * 32768) return;
    int b = id >> 15, r = id & 32767;
    float* st = state + (size_t)b * 32832;
    const float* fb = f2 + (size_t)b * 193 * SP;
    if (r < 8192) {
        int c = r >> 7, h = r & 127;
        const float* p = fb + (size_t)(64 + c) * SP + h * 128;
        float sum = 0.f;
        for (int w = 0; w < 128; w++) sum += p[w];
        st[64 + r] = sum * (1.f / 128.f);
    } else if (r < 16384) {
        int rr = r - 8192;
        int c = rr >> 7, w = rr & 127;
        const float* p = fb + (size_t)(128 + c) * SP + w;
        float sum = 0.f;
        for (int h = 0; h < 128; h++) sum += p[h << 7];
        st[8256 + rr] = sum * (1.f / 128.f);
    } else {
        int rr = r - 16384;
        st[16448 + rr] = fb[(size_t)192 * SP + rr];
    }
}

// ---------------------------------------------------------------------------
// k_gemv_big: k-split GEMV for huge W (row-major [K][N]).
// COLG = N/4 float4 col-groups; 256/COLG k-lanes per block.
// X chunk in LDS; float4 W loads, unroll 8 -> 8 in-flight 16B loads/thread.
// Grid.x = ceil(K/128). Atomic accumulate into out (pre-zeroed).
// ---------------------------------------------------------------------------
template<int COLG>
__global__ __launch_bounds__(256) void k_gemv_big(
    const float* __restrict__ W, const float* __restrict__ X,
    float* __restrict__ out, int K)
{
    constexpr int N = COLG * 4;
    constexpr int KL = 256 / COLG;
    const int tid = threadIdx.x;
    const int cg = tid % COLG;
    const int kl = tid / COLG;
    const int k0 = blockIdx.x * 128;
    const int iters = min(K - k0, 128);
    __shared__ float xs[4][128];
    for (int i = tid; i < 512; i += 256) {
        int b = i >> 7, k = i & 127;
        xs[b][k] = (k0 + k < K) ? X[(size_t)b * K + k0 + k] : 0.f;
    }
    __syncthreads();
    float4 a0 = {0,0,0,0}, a1 = {0,0,0,0}, a2 = {0,0,0,0}, a3 = {0,0,0,0};
    const float* wp = W + (size_t)k0 * N + cg * 4;
    #pragma unroll 8
    for (int k = kl; k < iters; k += KL) {
        float4 w4 = *(const float4*)(wp + (size_t)k * N);
        float x0 = xs[0][k], x1 = xs[1][k], x2 = xs[2][k], x3 = xs[3][k];
        a0.x += x0 * w4.x; a0.y += x0 * w4.y; a0.z += x0 * w4.z; a0.w += x0 * w4.w;
        a1.x += x1 * w4.x; a1.y += x1 * w4.y; a1.z += x1 * w4.z; a1.w += x1 * w4.w;
        a2.x += x2 * w4.x; a2.y += x2 * w4.y; a2.z += x2 * w4.z; a2.w += x2 * w4.w;
        a3.x += x3 * w4.x; a3.y += x3 * w4.y; a3.z += x3 * w4.z; a3.w += x3 * w4.w;
    }
    const int col = cg * 4;
    atomicAdd(&out[0 * N + col + 0], a0.x); atomicAdd(&out[0 * N + col + 1], a0.y);
    atomicAdd(&out[0 * N + col + 2], a0.z); atomicAdd(&out[0 * N + col + 3], a0.w);
    atomicAdd(&out[1 * N + col + 0], a1.x); atomicAdd(&out[1 * N + col + 1], a1.y);
    atomicAdd(&out[1 * N + col + 2], a1.z); atomicAdd(&out[1 * N + col + 3], a1.w);
    atomicAdd(&out[2 * N + col + 0], a2.x); atomicAdd(&out[2 * N + col + 1], a2.y);
    atomicAdd(&out[2 * N + col + 2], a2.z); atomicAdd(&out[2 * N + col + 3], a2.w);
    atomicAdd(&out[3 * N + col + 0], a3.x); atomicAdd(&out[3 * N + col + 1], a3.y);
    atomicAdd(&out[3 * N + col + 2], a3.z); atomicAdd(&out[3 * N + col + 3], a3.w);
}

__global__ void k_lrelu_bias(float* __restrict__ z, const float* __restrict__ bias, int N)
{
    int id = blockIdx.x * 256 + threadIdx.x;
    if (id < 4 * N) {
        float v = z[id] + bias[id % N];
        z[id] = v >= 0.f ? v : 0.2f * v;
    }
}

// ---------------------------------------------------------------------------
// k_mlp: small dense layer, k-split x col-split (see round-3 notes)
// ---------------------------------------------------------------------------
template<int ACT>
__global__ __launch_bounds__(256) void k_mlp(
    const float* __restrict__ X, const float* __restrict__ W,
    const float* __restrict__ bias, const float* __restrict__ skip,
    float* __restrict__ out, int K, int N)
{
    const int b = blockIdx.y;
    const int colL = threadIdx.x & 63;
    const int col = blockIdx.x * 64 + colL;
    const int kq = threadIdx.x >> 6;
    __shared__ float xs[1024];
    __shared__ float red[4][64];
    const float* x = X + (size_t)b * K;
    for (int i = threadIdx.x; i < K; i += 256) xs[i] = x[i];
    __syncthreads();
    float acc = 0.f;
    #pragma unroll 8
    for (int k = kq; k < K; k += 4)
        acc += xs[k] * W[(size_t)k * N + col];
    red[kq][colL] = acc;
    __syncthreads();
    if (kq == 0) {
        float v = red[0][colL] + red[1][colL] + red[2][colL] + red[3][colL]
                + bias[col] + (skip ? skip[(size_t)b * N + col] : 0.f);
        if (ACT) v = v >= 0.f ? v : 0.2f * v;
        out[(size_t)b * N + col] = v;
    }
}

// ---------------------------------------------------------------------------
extern "C" void kernel_launch(void* const* d_in, const int* in_sizes, int n_in,
                              void* d_out, int out_size, void* d_ws, size_t ws_size,
                              hipStream_t stream)
{
    const float* x       = (const float*)d_in[0];
    const float* inj_lat = (const float*)d_in[1];
    const float* in_w    = (const float*)d_in[2];
    const float* in_b    = (const float*)d_in[3];
    const float* rbin_w1 = (const float*)d_in[4];
    const float* rbin_b1 = (const float*)d_in[5];
    const float* rbin_w2 = (const float*)d_in[6];
    const float* rbin_b2 = (const float*)d_in[7];
    const float* leak    = (const float*)d_in[8];
    const float* hyper_w = (const float*)d_in[9];
    const float* hyper_b = (const float*)d_in[10];
    const float* rbout_w1= (const float*)d_in[11];
    const float* rbout_b1= (const float*)d_in[12];
    const float* rbout_w2= (const float*)d_in[13];
    const float* rbout_b2= (const float*)d_in[14];
    const float* outc_w  = (const float*)d_in[15];
    const float* outc_b  = (const float*)d_in[16];
    const float* l1a_w   = (const float*)d_in[17];
    const float* l1a_b   = (const float*)d_in[18];
    const float* l1b_w   = (const float*)d_in[19];
    const float* l1b_b   = (const float*)d_in[20];
    const float* l1s_w   = (const float*)d_in[21];
    const float* l2a_w   = (const float*)d_in[22];
    const float* l2a_b   = (const float*)d_in[23];
    const float* l2b_w   = (const float*)d_in[24];
    const float* l2b_b   = (const float*)d_in[25];
    const float* lat_w   = (const float*)d_in[26];
    const float* lat_b   = (const float*)d_in[27];
    float* out = (float*)d_out;

    // ---- workspace layout ----
    float* Wf     = (float*)d_ws;
    float* dp     = Wf + 0;          // 394752
    float* bias1p = Wf + 394752;     // 256
    float* bias2p = Wf + 395008;     // 256
    float* bias3p = Wf + 395264;     // 512
    float* ssum   = Wf + 395776;     // 3584
    float* smean  = Wf + 399360;     // 1792
    float* srstd  = Wf + 401152;     // 1792
    float* carryA = Wf + 402944;     // 4499456
    float* carryB = Wf + 4902400;    // 4499456
    ushortT* Wu   = (ushortT*)(Wf + 9401856);
    ushortT* Abf1 = Wu + 0;          // 114688
    ushortT* Abf2 = Wu + 114688;     // 16384
    ushortT* Abf3 = Wu + 131072;     // 262144
    ushortT* PH1  = Wu + 393216;     // 4499456
    ushortT* ybuf = Wu + 4892672;    // 8998912
    ushortT* PFEAT= Wu + 13891584;   // 35995648
    // post-scan aliases:
    float* f1    = (float*)(Wu + 393216);
    float* f2    = (float*)(Wu + 13891584);
    float* state = carryB;
    float* z1    = state + 131328;
    float* zS    = z1 + 4096;
    float* zres1 = zS + 2048;
    float* ztmp  = zres1 + 2048;
    float* zres2 = ztmp + 2048;

    // 1. carry init + input conv + rb2d
    hipMemsetAsync(carryA, 0, (size_t)4499456 * 4, stream);
    k_rb2d<0><<<dim3(256, 4), 256, 0, stream>>>(x, in_w, in_b, rbin_w1, rbin_b1,
                                                rbin_w2, rbin_b2, carryA);
    // 2. hypernet + static weight prep
    k_hyper<<<dim3(386), 256, 0, stream>>>(inj_lat, hyper_w, hyper_b, dp);
    k_prep_g2<<<dim3(64), 256, 0, stream>>>(dp, Abf2, bias2p);

    // 3. scan (4 steps)
    float* cs = carryA;
    float* cd = carryB;
    for (int step = 0; step < 4; step++) {
        hipMemsetAsync(ssum, 0, (size_t)3584 * 4, stream);
        k_conv<<<dim3(5, 64, 4), 256, 0, stream>>>(cs, PFEAT, ssum);
        k_stats_fin<<<dim3(7), 256, 0, stream>>>(ssum, smean, srstd);
        k_prep_dyn<<<dim3(768), 256, 0, stream>>>(dp, smean, srstd,
                                                  Abf1, bias1p, Abf3, bias3p);
        k_mfma<64, 1, 1><<<dim3(69, 1, 4), 256, 0, stream>>>(
            Abf1, PFEAT + (size_t)8 * S3 * 8, bias1p, PH1,
            (size_t)64 * S3 * 8, (size_t)8 * S3 * 8, 448);
        k_mfma<64, 1, 1><<<dim3(69, 1, 4), 256, 0, stream>>>(
            Abf2, PH1, bias2p, PFEAT,
            (size_t)8 * S3 * 8, (size_t)64 * S3 * 8, 64);
        k_mfma<128, 0, 0><<<dim3(138, 1, 4), 256, 0, stream>>>(
            Abf3, PFEAT, bias3p, ybuf,
            (size_t)64 * S3 * 8, (size_t)128 * S3, 512);
        k_glu<<<dim3(17576), 256, 0, stream>>>(ybuf, cs, cd, leak);
        float* t = cs; cs = cd; cd = t;
    }
    // cs == carryA (final)

    // 4. output rb2d + outc + reductions to state
    k_rb2d<1><<<dim3(256, 4), 256, 0, stream>>>(cs, nullptr, nullptr, rbout_w1,
                                                rbout_b1, rbout_w2, rbout_b2, f1);
    k_outc<<<dim3(512, 4), 256, 0, stream>>>(f1, outc_w, outc_b, f2);
    k_cf<<<dim3(64, 4), 256, 0, stream>>>(f2, state);
    k_state2<<<dim3(512), 256, 0, stream>>>(f2, state);

    // 5. MLP head
    hipMemsetAsync(z1, 0, (size_t)4096 * 4, stream);
    hipMemsetAsync(zS, 0, (size_t)2048 * 4, stream);
    k_gemv_big<256><<<dim3(257), 256, 0, stream>>>(l1a_w, state, z1, 32832);
    k_gemv_big<128><<<dim3(257), 256, 0, stream>>>(l1s_w, state, zS, 32832);
    k_lrelu_bias<<<dim3(16), 256, 0, stream>>>(z1, l1a_b, 1024);
    k_mlp<0><<<dim3(8, 4), 256, 0, stream>>>(z1, l1b_w, l1b_b, zS, zres1, 1024, 512);
    k_mlp<1><<<dim3(8, 4), 256, 0, stream>>>(zres1, l2a_w, l2a_b, nullptr, ztmp, 512, 512);
    k_mlp<0><<<dim3(8, 4), 256, 0, stream>>>(ztmp, l2b_w, l2b_b, zres1, zres2, 512, 512);
    k_mlp<0><<<dim3(8, 4), 256, 0, stream>>>(zres2, lat_w, lat_b, nullptr, out, 512, 512);
    (void)in_sizes; (void)n_in; (void)out_size; (void)ws_size;
}